// Round 1
// baseline (19254.102 us; speedup 1.0000x reference)
//
#include <hip/hip_runtime.h>
#include <math.h>

#ifndef DIVUP
#define DIVUP(a,b) (((a)+(b)-1)/(b))
#endif

// ---------------- shapes ----------------
#define BB 4
#define HH0 224
#define WW0 224
#define NGF 64
#define NZ 16
#define CTX 512
#define C4 256
#define N56 3136       // 56*56
#define N112 12544     // 112*112
#define N224 50176     // 224*224

static const float BN_ALPHA = 0.99999500003749967f;  // 1/sqrt(1+1e-5)

// ---------------- block reductions (blockDim = 256) ----------------
__device__ inline float blk_reduce_sum(float v, float* lds) {
  int t = threadIdx.x;
  lds[t] = v; __syncthreads();
  for (int s = 128; s > 0; s >>= 1) { if (t < s) lds[t] += lds[t + s]; __syncthreads(); }
  float r = lds[0]; __syncthreads();
  return r;
}
__device__ inline float blk_reduce_max(float v, float* lds) {
  int t = threadIdx.x;
  lds[t] = v; __syncthreads();
  for (int s = 128; s > 0; s >>= 1) { if (t < s) lds[t] = fmaxf(lds[t], lds[t + s]); __syncthreads(); }
  float r = lds[0]; __syncthreads();
  return r;
}

// ---------------- generic GEMM (C[b] = act(alpha*A·B^T*scale + bias + resid)) ----------------
// A-modes: 0 = strided, 1 = implicit im2col conv (+z channels), 2 = implicit convT (stride 2)
struct GemmArgs {
  const float* A; long long Am, Ak, Abatch;   // mode0 strides; modes1/2: Abatch = input batch stride
  const float* B; long long Bn, Bk, Bbatch;
  float*       C; long long Cm, Cn, Cbatch;
  const float* bias;                          // per-n, nullable
  const float* scale;                         // per-n (BN gamma), nullable
  const float* resid; long long Rm, Rn, Rbatch; // nullable
  float alpha;
  int relu;
  int M, N, K;
  int a_kfast, b_kfast;
  // conv params
  const float* z; int z_stride;               // z channels appended after Cin_main (mode 1)
  int Cin_main;
  int Hin, Win, Wout;
  int ks, stride, pad, reflect;
};

__device__ inline int refl_idx(int i, int n) {
  if (i < 0) i = -i;
  if (i >= n) i = 2 * n - 2 - i;
  return i;
}

template<int AMODE>
__device__ inline float loadA(const GemmArgs& g, int b, int m, int k) {
  if (k >= g.K) return 0.f;
  if (AMODE == 0) {
    return g.A[(long long)b * g.Abatch + (long long)m * g.Am + (long long)k * g.Ak];
  } else if (AMODE == 1) {
    int ks2 = g.ks * g.ks;
    int ic = k / ks2, t = k % ks2;
    int ky = t / g.ks, kx = t % g.ks;
    int y = m / g.Wout, x = m % g.Wout;
    int iy = y * g.stride + ky - g.pad;
    int ix = x * g.stride + kx - g.pad;
    if (g.reflect) {
      iy = refl_idx(iy, g.Hin); ix = refl_idx(ix, g.Win);
    } else {
      if (iy < 0 || iy >= g.Hin || ix < 0 || ix >= g.Win) return 0.f;
    }
    if (ic >= g.Cin_main) return g.z[b * g.z_stride + (ic - g.Cin_main)];
    return g.A[(long long)b * g.Abatch + ((long long)ic * g.Hin + iy) * g.Win + ix];
  } else {
    // convT: out[y,x] = sum_ic,ky,kx X(y+ky-1, x+kx-1) * Bprep, X valid iff coords even/2 in range
    int ic = k / 9, t = k % 9, ky = t / 3, kx = t % 3;
    int y = m / g.Wout, x = m % g.Wout;
    int iy2 = y + ky - 1, ix2 = x + kx - 1;
    if (iy2 < 0 || ix2 < 0 || (iy2 & 1) || (ix2 & 1)) return 0.f;
    int iy = iy2 >> 1, ix = ix2 >> 1;
    if (iy >= g.Hin || ix >= g.Win) return 0.f;
    return g.A[(long long)b * g.Abatch + ((long long)ic * g.Hin + iy) * g.Win + ix];
  }
}

__device__ inline float loadB(const GemmArgs& g, int b, int n, int k) {
  if (k >= g.K) return 0.f;
  return g.B[(long long)b * g.Bbatch + (long long)n * g.Bn + (long long)k * g.Bk];
}

template<int AMODE>
__global__ __launch_bounds__(256) void gemm_k(GemmArgs g) {
  __shared__ __align__(16) float As[16][68];
  __shared__ __align__(16) float Bs[16][68];
  const int tid = threadIdx.x;
  const int b  = blockIdx.z;
  const int m0 = blockIdx.y * 64;
  const int n0 = blockIdx.x * 64;
  const int mi = (tid >> 4) << 2;
  const int ni = (tid & 15) << 2;
  float acc[4][4] = {};
  const int nk = (g.K + 15) & ~15;
  for (int k0 = 0; k0 < nk; k0 += 16) {
    if (g.a_kfast) {
      int e = tid * 4;
      int k = e & 15, m = e >> 4;
      #pragma unroll
      for (int j = 0; j < 4; ++j)
        As[k + j][m] = loadA<AMODE>(g, b, m0 + m, k0 + k + j);
    } else {
      #pragma unroll
      for (int j = 0; j < 4; ++j) {
        int e = tid + 256 * j;
        int m = e & 63, k = e >> 6;
        As[k][m] = loadA<AMODE>(g, b, m0 + m, k0 + k);
      }
    }
    if (g.b_kfast) {
      int e = tid * 4;
      int k = e & 15, n = e >> 4;
      #pragma unroll
      for (int j = 0; j < 4; ++j)
        Bs[k + j][n] = loadB(g, b, n0 + n, k0 + k + j);
    } else {
      #pragma unroll
      for (int j = 0; j < 4; ++j) {
        int e = tid + 256 * j;
        int n = e & 63, k = e >> 6;
        Bs[k][n] = loadB(g, b, n0 + n, k0 + k);
      }
    }
    __syncthreads();
    #pragma unroll
    for (int kk = 0; kk < 16; ++kk) {
      float4 a4 = *(const float4*)&As[kk][mi];
      float4 b4 = *(const float4*)&Bs[kk][ni];
      float ar[4] = {a4.x, a4.y, a4.z, a4.w};
      float br[4] = {b4.x, b4.y, b4.z, b4.w};
      #pragma unroll
      for (int ii = 0; ii < 4; ++ii)
        #pragma unroll
        for (int jj = 0; jj < 4; ++jj)
          acc[ii][jj] = fmaf(ar[ii], br[jj], acc[ii][jj]);
    }
    __syncthreads();
  }
  #pragma unroll
  for (int ii = 0; ii < 4; ++ii) {
    int m = m0 + mi + ii;
    #pragma unroll
    for (int jj = 0; jj < 4; ++jj) {
      int n = n0 + ni + jj;
      float v = acc[ii][jj] * g.alpha;
      if (g.scale) v *= g.scale[n];
      if (g.bias)  v += g.bias[n];
      if (g.resid) v += g.resid[(long long)b * g.Rbatch + (long long)m * g.Rm + (long long)n * g.Rn];
      if (g.relu)  v = fmaxf(v, 0.f);
      g.C[(long long)b * g.Cbatch + (long long)m * g.Cm + (long long)n * g.Cn] = v;
    }
  }
}

// ---------------- spectral norm -> z (single block) ----------------
__global__ __launch_bounds__(256) void spectral_z_k(const float* __restrict__ cond,
    const float* __restrict__ W, const float* __restrict__ u0, float* __restrict__ z) {
  __shared__ float v0[512];
  __shared__ float lds[256];
  __shared__ float wv[16];
  __shared__ float invs[2];
  int tid = threadIdx.x;
  float part = 0.f;
  #pragma unroll
  for (int r = 0; r < 2; ++r) {
    int j = tid + r * 256;
    float s = 0.f;
    #pragma unroll
    for (int i = 0; i < 16; ++i) s = fmaf(W[i * 512 + j], u0[i], s);
    v0[j] = s;
    part = fmaf(s, s, part);
  }
  float nv2 = blk_reduce_sum(part, lds);
  if (tid == 0) invs[0] = 1.f / (sqrtf(nv2) + 1e-12f);
  __syncthreads();
  float inv_nv = invs[0];
  {
    int i = tid >> 4, l = tid & 15;
    float s = 0.f;
    for (int jj = 0; jj < 32; ++jj) {
      int j = l + jj * 16;
      s = fmaf(W[i * 512 + j], v0[j], s);
    }
    lds[tid] = s; __syncthreads();
    if (l == 0) {
      float t = 0.f;
      for (int q = 0; q < 16; ++q) t += lds[(i << 4) + q];
      wv[i] = t * inv_nv;
    }
    __syncthreads();
    if (tid == 0) {
      float s2 = 0.f;
      for (int i2 = 0; i2 < 16; ++i2) s2 = fmaf(wv[i2], wv[i2], s2);
      float nw = sqrtf(s2);
      float sigma = s2 / (nw + 1e-12f);
      invs[1] = 1.f / sigma;
    }
    __syncthreads();
  }
  if (tid < 64) {
    int b = tid >> 4, i = tid & 15;
    float s = 0.f;
    for (int j = 0; j < 512; ++j) s = fmaf(cond[b * 512 + j], W[i * 512 + j], s);
    z[b * 16 + i] = s * invs[1];
  }
}

// ---------------- convT weight prep: wt[o][ic][ky][kx] = w[ic][o][2-ky][2-kx] ----------------
__global__ void prep_wt_k(const float* __restrict__ w, float* __restrict__ wt, int Cin, int Cout) {
  int idx = blockIdx.x * 256 + threadIdx.x;
  int total = Cin * Cout * 9;
  if (idx >= total) return;
  int kx = idx % 3, ky = (idx / 3) % 3, ic = (idx / 9) % Cin, o = idx / (9 * Cin);
  wt[idx] = w[(((ic * Cout) + o) * 3 + (2 - ky)) * 3 + (2 - kx)];
}

// ---------------- group norm (32 groups) ----------------
__global__ __launch_bounds__(256) void groupnorm_k(const float* __restrict__ x, float* __restrict__ out,
    const float* __restrict__ gam, const float* __restrict__ bet, int C, int HW, int cpg) {
  __shared__ float lds[256];
  int b = blockIdx.y, grp = blockIdx.x;
  long long base = ((long long)b * C + (long long)grp * cpg) * HW;
  int n = cpg * HW;
  float s = 0.f, s2 = 0.f;
  for (int i = threadIdx.x; i < n; i += 256) { float v = x[base + i]; s += v; s2 = fmaf(v, v, s2); }
  s  = blk_reduce_sum(s, lds);
  s2 = blk_reduce_sum(s2, lds);
  float m = s / (float)n;
  float var = s2 / (float)n - m * m;
  float rinv = 1.f / sqrtf(var + 1e-6f);
  for (int i = threadIdx.x; i < n; i += 256) {
    int c = grp * cpg + i / HW;
    out[base + i] = (x[base + i] - m) * rinv * gam[c] + bet[c];
  }
}

// ---------------- layer norm over last dim 256 (one token per block) ----------------
__global__ __launch_bounds__(256) void layernorm_k(const float* __restrict__ x, float* __restrict__ out,
    const float* __restrict__ g, const float* __restrict__ b) {
  __shared__ float lds[256];
  long long t = blockIdx.x;
  float v = x[t * 256 + threadIdx.x];
  float s  = blk_reduce_sum(v, lds);
  float s2 = blk_reduce_sum(v * v, lds);
  float m = s * (1.f / 256.f);
  float var = s2 * (1.f / 256.f) - m * m;
  float rinv = 1.f / sqrtf(var + 1e-5f);
  out[t * 256 + threadIdx.x] = (v - m) * rinv * g[threadIdx.x] + b[threadIdx.x];
}

// ---------------- row softmax (one row per block) ----------------
__global__ __launch_bounds__(256) void softmax_k(float* __restrict__ S, int n) {
  __shared__ float lds[256];
  float* p = S + (long long)blockIdx.x * n;
  float mx = -3.4e38f;
  for (int i = threadIdx.x; i < n; i += 256) mx = fmaxf(mx, p[i]);
  mx = blk_reduce_max(mx, lds);
  float s = 0.f;
  for (int i = threadIdx.x; i < n; i += 256) { float e = __expf(p[i] - mx); p[i] = e; s += e; }
  s = blk_reduce_sum(s, lds);
  float inv = 1.f / s;
  for (int i = threadIdx.x; i < n; i += 256) p[i] *= inv;
}

// ---------------- GEGLU in-place on (ntok, 2048): p[:, :1024] = a * gelu(gate) ----------------
__global__ void geglu_k(float* __restrict__ p, int ntok) {
  int idx = blockIdx.x * 256 + threadIdx.x;
  if (idx >= ntok * 1024) return;
  int t = idx >> 10, j = idx & 1023;
  float a  = p[t * 2048 + j];
  float gt = p[t * 2048 + 1024 + j];
  float ge = 0.5f * gt * (1.f + erff(gt * 0.70710678118654752f));
  p[t * 2048 + j] = a * ge;
}

// ---------------- degenerate cross-attn: o2[b] = (cond@Wv^T)@Wo^T + bo ----------------
__global__ __launch_bounds__(256) void crossattn_vec_k(const float* __restrict__ cond,
    const float* __restrict__ v2w, const float* __restrict__ o2w, const float* __restrict__ o2b,
    float* __restrict__ o2buf) {
  __shared__ float kv[256];
  int b = blockIdx.x, oc = threadIdx.x;
  float s = 0.f;
  for (int j = 0; j < 512; ++j) s = fmaf(cond[b * 512 + j], v2w[oc * 512 + j], s);
  kv[oc] = s; __syncthreads();
  float o = o2b[oc];
  for (int ic = 0; ic < 256; ++ic) o = fmaf(kv[ic], o2w[oc * 256 + ic], o);
  o2buf[b * 256 + oc] = o;
}
__global__ void bcast_add_k(float* __restrict__ T, const float* __restrict__ o2buf, int ntok_per_b) {
  long long idx = (long long)blockIdx.x * 256 + threadIdx.x;
  int c = (int)(idx & 255);
  long long tb = idx >> 8;
  int b = (int)(tb / ntok_per_b);
  T[idx] += o2buf[b * 256 + c];
}

// ---------------- final 7x7 conv (64->3, reflect 3) + bias + tanh ----------------
__global__ __launch_bounds__(256) void conv_final_k(const float* __restrict__ in,
    const float* __restrict__ w, const float* __restrict__ bias, float* __restrict__ out) {
  __shared__ float wl[3 * 64 * 49];
  for (int i = threadIdx.x; i < 3 * 64 * 49; i += 256) wl[i] = w[i];
  __syncthreads();
  int b = blockIdx.y;
  int p = blockIdx.x * 256 + threadIdx.x;
  int y = p / 224, x = p % 224;
  int iy[7], ix[7];
  #pragma unroll
  for (int t = 0; t < 7; ++t) {
    int a = y + t - 3; iy[t] = (a < 0) ? -a : ((a >= 224) ? 446 - a : a);
    int c = x + t - 3; ix[t] = (c < 0) ? -c : ((c >= 224) ? 446 - c : c);
  }
  float a0 = bias[0], a1 = bias[1], a2 = bias[2];
  for (int ic = 0; ic < 64; ++ic) {
    const float* ip = in + (long long)(b * 64 + ic) * N224;
    const float* w0 = &wl[(0 * 64 + ic) * 49];
    const float* w1 = &wl[(1 * 64 + ic) * 49];
    const float* w2 = &wl[(2 * 64 + ic) * 49];
    #pragma unroll
    for (int ky = 0; ky < 7; ++ky) {
      const float* rp = ip + iy[ky] * 224;
      #pragma unroll
      for (int kx = 0; kx < 7; ++kx) {
        float v = rp[ix[kx]];
        int t = ky * 7 + kx;
        a0 = fmaf(v, w0[t], a0);
        a1 = fmaf(v, w1[t], a1);
        a2 = fmaf(v, w2[t], a2);
      }
    }
  }
  long long ob = (long long)b * 3 * N224 + p;
  out[ob]            = tanhf(a0);
  out[ob + N224]     = tanhf(a1);
  out[ob + 2 * N224] = tanhf(a2);
}

// ---------------- 3x3 gaussian blur (zero pad) * eps ----------------
__global__ void blur_k(const float* __restrict__ x, float* __restrict__ out, const int* __restrict__ epsp) {
  int idx = blockIdx.x * 256 + threadIdx.x;
  // total = 4*3*224*224 = 602112, exact multiple of 256
  int xp = idx % 224;
  int y  = (idx / 224) % 224;
  int bc = idx / N224;
  const float* p = x + (long long)bc * N224;
  const float kc = 0.20417996f, k1 = 0.12384140f, k2 = 0.07511360f;
  float s = 0.f;
  #pragma unroll
  for (int dy = -1; dy <= 1; ++dy) {
    int yy = y + dy;
    if (yy < 0 || yy >= 224) continue;
    #pragma unroll
    for (int dx = -1; dx <= 1; ++dx) {
      int xx = xp + dx;
      if (xx < 0 || xx >= 224) continue;
      float wgt = (dy == 0 && dx == 0) ? kc : ((dy != 0 && dx != 0) ? k2 : k1);
      s = fmaf(p[yy * 224 + xx], wgt, s);
    }
  }
  out[idx] = s * (float)epsp[0];
}

// ---------------- host side ----------------
static inline GemmArgs GA() { GemmArgs g = {}; g.alpha = 1.f; return g; }

static inline void run_gemm(hipStream_t s, int amode, const GemmArgs& g, int zb) {
  dim3 grid(g.N / 64, (g.M + 63) / 64, zb);
  if (amode == 0)      gemm_k<0><<<grid, 256, 0, s>>>(g);
  else if (amode == 1) gemm_k<1><<<grid, 256, 0, s>>>(g);
  else                 gemm_k<2><<<grid, 256, 0, s>>>(g);
}

extern "C" void kernel_launch(void* const* d_in, const int* in_sizes, int n_in,
                              void* d_out, int out_size, void* d_ws, size_t ws_size,
                              hipStream_t stream) {
  (void)in_sizes; (void)n_in; (void)out_size; (void)ws_size;
  const float* input = (const float*)d_in[0];
  const float* cond  = (const float*)d_in[1];
  const float* sn_w  = (const float*)d_in[2];
  const float* sn_u  = (const float*)d_in[3];
  const float* c1_w  = (const float*)d_in[4];
  const float* bn1_g = (const float*)d_in[5];
  const float* bn1_b = (const float*)d_in[6];
  const float* c2_w  = (const float*)d_in[7];
  const float* bn2_g = (const float*)d_in[8];
  const float* bn2_b = (const float*)d_in[9];
  const float* c3_w  = (const float*)d_in[10];
  const float* bn3_g = (const float*)d_in[11];
  const float* bn3_b = (const float*)d_in[12];
  const float* res_w = (const float*)d_in[13];
  const float* res_g = (const float*)d_in[14];
  const float* res_b = (const float*)d_in[15];
  const float* gn_g  = (const float*)d_in[16];
  const float* gn_b  = (const float*)d_in[17];
  const float* pin_w = (const float*)d_in[18];
  const float* pin_b = (const float*)d_in[19];
  const float* q1w   = (const float*)d_in[20];
  const float* k1w   = (const float*)d_in[21];
  const float* v1w   = (const float*)d_in[22];
  const float* o1w   = (const float*)d_in[23];
  const float* o1b   = (const float*)d_in[24];
  /* 25 st_q2, 26 st_k2: dead (cross-attn keys have length 1 -> softmax == 1) */
  const float* v2w   = (const float*)d_in[27];
  const float* o2w   = (const float*)d_in[28];
  const float* o2b   = (const float*)d_in[29];
  const float* ffpw  = (const float*)d_in[30];
  const float* ffpb  = (const float*)d_in[31];
  const float* ffow  = (const float*)d_in[32];
  const float* ffob  = (const float*)d_in[33];
  const float* ln1g  = (const float*)d_in[34];
  const float* ln1b  = (const float*)d_in[35];
  /* 36,37: ln2 dead */
  const float* ln3g  = (const float*)d_in[38];
  const float* ln3b  = (const float*)d_in[39];
  const float* poutw = (const float*)d_in[40];
  const float* poutb = (const float*)d_in[41];
  const float* up1w  = (const float*)d_in[42];
  const float* up1g  = (const float*)d_in[43];
  const float* up1b  = (const float*)d_in[44];
  const float* up2w  = (const float*)d_in[45];
  const float* up2g  = (const float*)d_in[46];
  const float* up2b  = (const float*)d_in[47];
  const float* cfw   = (const float*)d_in[48];
  const float* cfb   = (const float*)d_in[49];
  const int*   epsp  = (const int*)d_in[50];

  // ---- workspace arena (~226 MB) ----
  char* w = (char*)d_ws;
  size_t off = 0;
  auto alloc = [&](size_t bytes) { float* p = (float*)(w + off); off += (bytes + 255) & ~(size_t)255; return p; };
  float* Zb  = alloc(BB * NZ * 4);
  float* O2  = alloc(BB * C4 * 4);
  float* WT1 = alloc((size_t)128 * 256 * 9 * 4);
  float* WT2 = alloc((size_t)64 * 128 * 9 * 4);
  float* A1  = alloc((size_t)BB * 64 * N224 * 4);    // (4,64,224,224)
  float* A2  = alloc((size_t)BB * 128 * N112 * 4);   // (4,128,112,112)
  float* X   = alloc((size_t)BB * C4 * N56 * 4);     // current 56x56 features
  float* T   = alloc((size_t)BB * N56 * C4 * 4);     // tokens (b, n, c)
  float* Hb  = alloc((size_t)BB * C4 * N56 * 4);     // temp (NCHW or tokens)
  float* Qb  = alloc((size_t)BB * N56 * C4 * 4);
  float* Kb  = alloc((size_t)BB * N56 * C4 * 4);
  float* Vb  = alloc((size_t)BB * N56 * C4 * 4);
  float* AO  = alloc((size_t)BB * N56 * C4 * 4);
  float* SIM = alloc((size_t)N56 * N56 * 4);         // per-batch score matrix
  float* FF  = alloc((size_t)N56 * 2048 * 4);        // per-batch FF buffer
  float* CF  = alloc((size_t)BB * 3 * N224 * 4);

  const long long S56 = (long long)C4 * N56;  // 802816

  // 1) z from spectral-norm path
  spectral_z_k<<<1, 256, 0, stream>>>(cond, sn_w, sn_u, Zb);
  // 2) convT weight re-layout
  prep_wt_k<<<DIVUP(256 * 128 * 9, 256), 256, 0, stream>>>(up1w, WT1, 256, 128);
  prep_wt_k<<<DIVUP(128 * 64 * 9, 256), 256, 0, stream>>>(up2w, WT2, 128, 64);

  // 3) c1: 7x7 reflect(3), (3+16)->64, BN+ReLU
  {
    GemmArgs g = GA();
    g.A = input; g.Abatch = 3LL * N224;
    g.z = Zb; g.z_stride = NZ; g.Cin_main = 3;
    g.Hin = 224; g.Win = 224; g.Wout = 224; g.ks = 7; g.stride = 1; g.pad = 3; g.reflect = 1;
    g.B = c1_w; g.Bn = 931; g.Bk = 1; g.b_kfast = 1;
    g.C = A1; g.Cm = 1; g.Cn = N224; g.Cbatch = 64LL * N224;
    g.scale = bn1_g; g.bias = bn1_b; g.alpha = BN_ALPHA; g.relu = 1;
    g.M = N224; g.N = 64; g.K = 931;
    run_gemm(stream, 1, g, BB);
  }
  // 4) c2: 3x3 s2 zero-pad 1, (64+16)->128
  {
    GemmArgs g = GA();
    g.A = A1; g.Abatch = 64LL * N224;
    g.z = Zb; g.z_stride = NZ; g.Cin_main = 64;
    g.Hin = 224; g.Win = 224; g.Wout = 112; g.ks = 3; g.stride = 2; g.pad = 1; g.reflect = 0;
    g.B = c2_w; g.Bn = 720; g.Bk = 1; g.b_kfast = 1;
    g.C = A2; g.Cm = 1; g.Cn = N112; g.Cbatch = 128LL * N112;
    g.scale = bn2_g; g.bias = bn2_b; g.alpha = BN_ALPHA; g.relu = 1;
    g.M = N112; g.N = 128; g.K = 720;
    run_gemm(stream, 1, g, BB);
  }
  // 5) c3: 3x3 s2 zero-pad 1, (128+16)->256
  {
    GemmArgs g = GA();
    g.A = A2; g.Abatch = 128LL * N112;
    g.z = Zb; g.z_stride = NZ; g.Cin_main = 128;
    g.Hin = 112; g.Win = 112; g.Wout = 56; g.ks = 3; g.stride = 2; g.pad = 1; g.reflect = 0;
    g.B = c3_w; g.Bn = 1296; g.Bk = 1; g.b_kfast = 1;
    g.C = X; g.Cm = 1; g.Cn = N56; g.Cbatch = S56;
    g.scale = bn3_g; g.bias = bn3_b; g.alpha = BN_ALPHA; g.relu = 1;
    g.M = N56; g.N = 256; g.K = 1296;
    run_gemm(stream, 1, g, BB);
  }

  auto resblock = [&](int r) {
    {
      GemmArgs g = GA();
      g.A = X; g.Abatch = S56; g.Cin_main = 256;
      g.Hin = 56; g.Win = 56; g.Wout = 56; g.ks = 3; g.stride = 1; g.pad = 1; g.reflect = 1;
      g.B = res_w + (size_t)(r * 2) * 589824; g.Bn = 2304; g.Bk = 1; g.b_kfast = 1;
      g.C = Hb; g.Cm = 1; g.Cn = N56; g.Cbatch = S56;
      g.scale = res_g + (r * 2) * 256; g.bias = res_b + (r * 2) * 256;
      g.alpha = BN_ALPHA; g.relu = 1;
      g.M = N56; g.N = 256; g.K = 2304;
      run_gemm(stream, 1, g, BB);
    }
    {
      GemmArgs g = GA();
      g.A = Hb; g.Abatch = S56; g.Cin_main = 256;
      g.Hin = 56; g.Win = 56; g.Wout = 56; g.ks = 3; g.stride = 1; g.pad = 1; g.reflect = 1;
      g.B = res_w + (size_t)(r * 2 + 1) * 589824; g.Bn = 2304; g.Bk = 1; g.b_kfast = 1;
      g.C = X; g.Cm = 1; g.Cn = N56; g.Cbatch = S56;
      g.scale = res_g + (r * 2 + 1) * 256; g.bias = res_b + (r * 2 + 1) * 256;
      g.alpha = BN_ALPHA; g.relu = 0;
      g.resid = X; g.Rm = 1; g.Rn = N56; g.Rbatch = S56;
      g.M = N56; g.N = 256; g.K = 2304;
      run_gemm(stream, 1, g, BB);
    }
  };

  auto transformer = [&](int i) {
    // GN
    groupnorm_k<<<dim3(32, BB), 256, 0, stream>>>(X, Hb, gn_g + i * 256, gn_b + i * 256, 256, N56, 8);
    // proj_in: NCHW -> tokens, +bias
    {
      GemmArgs g = GA();
      g.A = Hb; g.Am = 1; g.Ak = N56; g.Abatch = S56; g.a_kfast = 0;
      g.B = pin_w + (size_t)i * 65536; g.Bn = 256; g.Bk = 1; g.b_kfast = 1;
      g.C = T; g.Cm = 256; g.Cn = 1; g.Cbatch = S56;
      g.bias = pin_b + i * 256;
      g.M = N56; g.N = 256; g.K = 256;
      run_gemm(stream, 0, g, BB);
    }
    // LN1 -> Hb (tokens)
    layernorm_k<<<BB * N56, 256, 0, stream>>>(T, Hb, ln1g + i * 256, ln1b + i * 256);
    // Q,K,V projections
    for (int which = 0; which < 3; ++which) {
      GemmArgs g = GA();
      g.A = Hb; g.Am = 256; g.Ak = 1; g.Abatch = S56; g.a_kfast = 1;
      g.B = (which == 0 ? q1w : which == 1 ? k1w : v1w) + (size_t)i * 65536;
      g.Bn = 256; g.Bk = 1; g.b_kfast = 1;
      g.C = (which == 0 ? Qb : which == 1 ? Kb : Vb); g.Cm = 256; g.Cn = 1; g.Cbatch = S56;
      g.M = N56; g.N = 256; g.K = 256;
      run_gemm(stream, 0, g, BB);
    }
    // self-attention, per batch (SIM buffer reused)
    for (int b = 0; b < BB; ++b) {
      {
        GemmArgs g = GA();
        g.A = Qb + (size_t)b * S56; g.Am = 256; g.Ak = 1; g.a_kfast = 1;
        g.B = Kb + (size_t)b * S56; g.Bn = 256; g.Bk = 1; g.b_kfast = 1;
        g.C = SIM; g.Cm = N56; g.Cn = 1;
        g.alpha = 0.0625f;
        g.M = N56; g.N = N56; g.K = 256;
        run_gemm(stream, 0, g, 1);
      }
      softmax_k<<<N56, 256, 0, stream>>>(SIM, N56);
      {
        GemmArgs g = GA();
        g.A = SIM; g.Am = N56; g.Ak = 1; g.a_kfast = 1;
        g.B = Vb + (size_t)b * S56; g.Bn = 1; g.Bk = 256; g.b_kfast = 0;
        g.C = AO + (size_t)b * S56; g.Cm = 256; g.Cn = 1;
        g.M = N56; g.N = 256; g.K = N56;
        run_gemm(stream, 0, g, 1);
      }
    }
    // out-proj + residual into T
    {
      GemmArgs g = GA();
      g.A = AO; g.Am = 256; g.Ak = 1; g.Abatch = S56; g.a_kfast = 1;
      g.B = o1w + (size_t)i * 65536; g.Bn = 256; g.Bk = 1; g.b_kfast = 1;
      g.C = T; g.Cm = 256; g.Cn = 1; g.Cbatch = S56;
      g.bias = o1b + i * 256;
      g.resid = T; g.Rm = 256; g.Rn = 1; g.Rbatch = S56;
      g.M = N56; g.N = 256; g.K = 256;
      run_gemm(stream, 0, g, BB);
    }
    // degenerate cross-attn
    crossattn_vec_k<<<BB, 256, 0, stream>>>(cond, v2w + (size_t)i * 131072,
                                            o2w + (size_t)i * 65536, o2b + i * 256, O2);
    bcast_add_k<<<BB * N56, 256, 0, stream>>>(T, O2, N56);
    // LN3 -> Hb
    layernorm_k<<<BB * N56, 256, 0, stream>>>(T, Hb, ln3g + i * 256, ln3b + i * 256);
    // GEGLU FF, per batch
    for (int b = 0; b < BB; ++b) {
      {
        GemmArgs g = GA();
        g.A = Hb + (size_t)b * S56; g.Am = 256; g.Ak = 1; g.a_kfast = 1;
        g.B = ffpw + (size_t)i * 524288; g.Bn = 256; g.Bk = 1; g.b_kfast = 1;
        g.C = FF; g.Cm = 2048; g.Cn = 1;
        g.bias = ffpb + i * 2048;
        g.M = N56; g.N = 2048; g.K = 256;
        run_gemm(stream, 0, g, 1);
      }
      geglu_k<<<DIVUP(N56 * 1024, 256), 256, 0, stream>>>(FF, N56);
      {
        GemmArgs g = GA();
        g.A = FF; g.Am = 2048; g.Ak = 1; g.a_kfast = 1;
        g.B = ffow + (size_t)i * 262144; g.Bn = 1024; g.Bk = 1; g.b_kfast = 1;
        g.C = T + (size_t)b * S56; g.Cm = 256; g.Cn = 1;
        g.bias = ffob + i * 256;
        g.resid = T + (size_t)b * S56; g.Rm = 256; g.Rn = 1;
        g.M = N56; g.N = 256; g.K = 1024;
        run_gemm(stream, 0, g, 1);
      }
    }
    // proj_out: tokens -> NCHW, + residual X
    {
      GemmArgs g = GA();
      g.A = T; g.Am = 256; g.Ak = 1; g.Abatch = S56; g.a_kfast = 1;
      g.B = poutw + (size_t)i * 65536; g.Bn = 256; g.Bk = 1; g.b_kfast = 1;
      g.C = X; g.Cm = 1; g.Cn = N56; g.Cbatch = S56;
      g.bias = poutb + i * 256;
      g.resid = X; g.Rm = 1; g.Rn = N56; g.Rbatch = S56;
      g.M = N56; g.N = 256; g.K = 256;
      run_gemm(stream, 0, g, BB);
    }
  };

  resblock(0); resblock(1);
  transformer(0);
  resblock(2); resblock(3);
  transformer(1);
  resblock(4); resblock(5);

  // up1: convT 256->128, 56->112, BN+ReLU
  {
    GemmArgs g = GA();
    g.A = X; g.Abatch = S56;
    g.Hin = 56; g.Win = 56; g.Wout = 112;
    g.B = WT1; g.Bn = 2304; g.Bk = 1; g.b_kfast = 1;
    g.C = A2; g.Cm = 1; g.Cn = N112; g.Cbatch = 128LL * N112;
    g.scale = up1g; g.bias = up1b; g.alpha = BN_ALPHA; g.relu = 1;
    g.M = N112; g.N = 128; g.K = 2304;
    run_gemm(stream, 2, g, BB);
  }
  // up2: convT 128->64, 112->224, BN+ReLU
  {
    GemmArgs g = GA();
    g.A = A2; g.Abatch = 128LL * N112;
    g.Hin = 112; g.Win = 112; g.Wout = 224;
    g.B = WT2; g.Bn = 1152; g.Bk = 1; g.b_kfast = 1;
    g.C = A1; g.Cm = 1; g.Cn = N224; g.Cbatch = 64LL * N224;
    g.scale = up2g; g.bias = up2b; g.alpha = BN_ALPHA; g.relu = 1;
    g.M = N224; g.N = 64; g.K = 1152;
    run_gemm(stream, 2, g, BB);
  }
  // final conv + tanh, then gaussian blur * eps -> d_out
  conv_final_k<<<dim3(N224 / 256, BB), 256, 0, stream>>>(A1, cfw, cfb, CF);
  blur_k<<<DIVUP(BB * 3 * N224, 256), 256, 0, stream>>>(CF, (float*)d_out, epsp);
}

// Round 4
// 11023.732 us; speedup vs baseline: 1.7466x; 1.7466x over previous
//
#include <hip/hip_runtime.h>
#include <math.h>

#ifndef DIVUP
#define DIVUP(a,b) (((a)+(b)-1)/(b))
#endif

typedef unsigned short ushort_t;
typedef __attribute__((ext_vector_type(8))) short v8s;
typedef __attribute__((ext_vector_type(4))) float v4f;

#define BB 4
#define NZ 16
#define C4 256
#define N56 3136
#define N112 12544
#define N224 50176

static const float BN_ALPHA = 0.99999500003749967f;  // 1/sqrt(1+1e-5)

// ---------------- helpers ----------------
__device__ inline int refl_idx(int i, int n) {
  if (i < 0) i = -i;
  if (i >= n) i = 2 * n - 2 - i;
  return i;
}

// RNE split: v ~= hi + lo (both bf16)
__device__ inline void bsplit(float v, ushort_t& h, ushort_t& l) {
  unsigned b = __float_as_uint(v);
  unsigned r = (b + 0x7FFFu + ((b >> 16) & 1u)) & 0xFFFF0000u;
  h = (ushort_t)(r >> 16);
  float lo = v - __uint_as_float(r);
  unsigned bl_ = __float_as_uint(lo);
  unsigned rl = bl_ + 0x7FFFu + ((bl_ >> 16) & 1u);
  l = (ushort_t)(rl >> 16);
}

__device__ inline float blk_reduce_sum(float v, float* lds) {
  int t = threadIdx.x;
  lds[t] = v; __syncthreads();
  for (int s = 128; s > 0; s >>= 1) { if (t < s) lds[t] += lds[t + s]; __syncthreads(); }
  float r = lds[0]; __syncthreads();
  return r;
}
__device__ inline float blk_reduce_max(float v, float* lds) {
  int t = threadIdx.x;
  lds[t] = v; __syncthreads();
  for (int s = 128; s > 0; s >>= 1) { if (t < s) lds[t] = fmaxf(lds[t], lds[t + s]); __syncthreads(); }
  float r = lds[0]; __syncthreads();
  return r;
}

// ---------------- MFMA GEMM ----------------
// C[b][m][n] = act( alpha*scale[n] * sum_k A[m][k]*W[n][k] + bias[n] + resid )
// AMODE: 0 strided A; 1 implicit im2col conv (phase-major K, +z); 2 implicit convT
// BSPLIT: 1 = B pre-split ushort hi/lo; 0 = B fp32 (split inline)
struct MArgs {
  const float* A; long long Am, Ak, Abatch;          // AMODE 0
  const float* Xp; long long Xbatch;                 // AMODE 1/2 (NCHW input)
  const float* z;                                    // appended channels (AMODE 1)
  const ushort_t* Bh; const ushort_t* Bl;            // BSPLIT=1
  const float* Bf; long long Bbatch;                 // BSPLIT=0
  long long Bstride;                                 // row length (= padded K)
  float* C; long long Cm, Cn, Cbatch;
  const float* scale; const float* bias;
  const float* resid; long long Rm, Rn, Rbatch;
  float alpha; int relu;
  int M, N;
  int ICP, NPH;                                      // K = ICP*NPH (mult of 32)
  int Cin;                                           // real channels (conv)
  int KS, Hin, Win, Wout, stride, pad, reflect;
};

template<int AMODE, int TILE, int BSPLIT>
__global__ __launch_bounds__(256, 2) void mg_k(MArgs g) {
  constexpr int BMN = TILE ? 64 : 128;
  constexpr int EPT = BMN / 8;           // k-elems per thread per operand
  constexpr int MF  = TILE ? 2 : 4;      // 16x16 frags per wave per dim
  constexpr int LDSW = 40;               // padded row (ushorts) = 80B (16B-aligned pitch)
  __shared__ __align__(16) ushort_t sAh[BMN * LDSW];
  __shared__ __align__(16) ushort_t sAl[BMN * LDSW];
  __shared__ __align__(16) ushort_t sBh[BMN * LDSW];
  __shared__ __align__(16) ushort_t sBl[BMN * LDSW];

  const int tid = threadIdx.x;
  const int b = blockIdx.z;
  const int m0 = blockIdx.y * BMN, n0 = blockIdx.x * BMN;
  const int lane = tid & 63, w = tid >> 6;
  const int wm = (w >> 1) * (MF * 16), wn = (w & 1) * (MF * 16);

  const int srow = tid & (BMN - 1);
  const int skoff = (tid / BMN) * EPT;

  // ---- A setup ----
  int am = m0 + srow; if (am >= g.M) am = g.M - 1;
  int cy = 0, cx = 0;
  const float* Aptr;
  if (AMODE == 0) {
    Aptr = g.A + (long long)b * g.Abatch + (long long)am * g.Am;
  } else {
    cy = am / g.Wout; cx = am - cy * g.Wout;
    Aptr = g.Xp + (long long)b * g.Xbatch;
  }
  const int HW = g.Hin * g.Win;

  // ---- B setup ----
  int bn = n0 + srow; if (bn >= g.N) bn = g.N - 1;
  const ushort_t* BhP = BSPLIT ? (g.Bh + (long long)bn * g.Bstride + skoff) : nullptr;
  const ushort_t* BlP = BSPLIT ? (g.Bl + (long long)bn * g.Bstride + skoff) : nullptr;
  const float* BfP = BSPLIT ? nullptr : (g.Bf + (long long)b * g.Bbatch + (long long)bn * g.Bstride + skoff);

  // phase state (conv modes)
  int ph = 0, ic0 = 0, pbase = 0;
  bool pvalid = true;
  int kglob = 0;

  float areg[EPT];
  ushort_t bregh[EPT], bregl[EPT];
  float bregf[EPT];

  auto fetchA = [&]() {
    if (AMODE == 0) {
      const float* Ap = Aptr + (long long)(kglob + skoff) * g.Ak;
      if (g.Ak == 1) {
        #pragma unroll
        for (int e = 0; e < EPT; ++e) areg[e] = Ap[e];
      } else {
        #pragma unroll
        for (int e = 0; e < EPT; ++e) areg[e] = Ap[(long long)e * g.Ak];
      }
      kglob += 32;
    } else {
      if (ic0 == 0) {
        int ky = ph / g.KS, kx = ph - ky * g.KS;
        if (AMODE == 1) {
          int iy = cy * g.stride + ky - g.pad;
          int ix = cx * g.stride + kx - g.pad;
          if (g.reflect) {
            iy = refl_idx(iy, g.Hin); ix = refl_idx(ix, g.Win); pvalid = true;
          } else {
            pvalid = (iy >= 0 && iy < g.Hin && ix >= 0 && ix < g.Win);
            if (iy < 0) iy = 0; if (iy >= g.Hin) iy = g.Hin - 1;
            if (ix < 0) ix = 0; if (ix >= g.Win) ix = g.Win - 1;
          }
          pbase = iy * g.Win + ix;
        } else {
          int iy2 = cy + ky - 1, ix2 = cx + kx - 1;
          pvalid = (iy2 >= 0) && (ix2 >= 0) && !(iy2 & 1) && !(ix2 & 1);
          int iy = iy2 >> 1, ix = ix2 >> 1;
          if (pvalid && (iy >= g.Hin || ix >= g.Win)) pvalid = false;
          if (!pvalid) { iy = 0; ix = 0; }
          pbase = iy * g.Win + ix;
        }
      }
      #pragma unroll
      for (int e = 0; e < EPT; ++e) {
        int ic = ic0 + skoff + e;
        float v = 0.f;
        if (pvalid) {
          if (ic < g.Cin) v = Aptr[pbase + ic * HW];
          else if (g.z && ic < g.Cin + NZ) v = g.z[b * NZ + (ic - g.Cin)];
        }
        areg[e] = v;
      }
      ic0 += 32; if (ic0 == g.ICP) { ic0 = 0; ++ph; }
    }
  };

  auto fetchB = [&](int k0) {
    if (BSPLIT) {
      #pragma unroll
      for (int e = 0; e < EPT; ++e) { bregh[e] = BhP[k0 + e]; bregl[e] = BlP[k0 + e]; }
    } else {
      #pragma unroll
      for (int e = 0; e < EPT; ++e) bregf[e] = BfP[k0 + e];
    }
  };

  v4f acc[MF][MF];
  #pragma unroll
  for (int i = 0; i < MF; ++i)
    #pragma unroll
    for (int j = 0; j < MF; ++j) acc[i][j] = (v4f)(0.f);

  const int nt = (g.ICP * g.NPH) / 32;
  fetchA(); fetchB(0);

  const int fr = lane & 15, fk = (lane >> 4) * 8;

  for (int t = 0; t < nt; ++t) {
    __syncthreads();
    {
      ushort_t ah[EPT], al[EPT];
      #pragma unroll
      for (int e = 0; e < EPT; ++e) bsplit(areg[e], ah[e], al[e]);
      #pragma unroll
      for (int e = 0; e < EPT; ++e) { sAh[srow * LDSW + skoff + e] = ah[e]; sAl[srow * LDSW + skoff + e] = al[e]; }
      if (BSPLIT) {
        #pragma unroll
        for (int e = 0; e < EPT; ++e) { sBh[srow * LDSW + skoff + e] = bregh[e]; sBl[srow * LDSW + skoff + e] = bregl[e]; }
      } else {
        ushort_t bh[EPT], bl[EPT];
        #pragma unroll
        for (int e = 0; e < EPT; ++e) bsplit(bregf[e], bh[e], bl[e]);
        #pragma unroll
        for (int e = 0; e < EPT; ++e) { sBh[srow * LDSW + skoff + e] = bh[e]; sBl[srow * LDSW + skoff + e] = bl[e]; }
      }
    }
    __syncthreads();
    if (t + 1 < nt) { fetchA(); fetchB((t + 1) * 32); }
    {
      v8s fah[MF], fal[MF], fbh[MF], fbl[MF];
      #pragma unroll
      for (int i = 0; i < MF; ++i) {
        fah[i] = *(const v8s*)&sAh[(wm + i * 16 + fr) * LDSW + fk];
        fal[i] = *(const v8s*)&sAl[(wm + i * 16 + fr) * LDSW + fk];
        fbh[i] = *(const v8s*)&sBh[(wn + i * 16 + fr) * LDSW + fk];
        fbl[i] = *(const v8s*)&sBl[(wn + i * 16 + fr) * LDSW + fk];
      }
      #pragma unroll
      for (int i = 0; i < MF; ++i)
        #pragma unroll
        for (int j = 0; j < MF; ++j) {
          acc[i][j] = __builtin_amdgcn_mfma_f32_16x16x32_bf16(fah[i], fbh[j], acc[i][j], 0, 0, 0);
          acc[i][j] = __builtin_amdgcn_mfma_f32_16x16x32_bf16(fah[i], fbl[j], acc[i][j], 0, 0, 0);
          acc[i][j] = __builtin_amdgcn_mfma_f32_16x16x32_bf16(fal[i], fbh[j], acc[i][j], 0, 0, 0);
        }
    }
  }

  // epilogue: C/D layout col=lane&15, row=(lane>>4)*4+reg
  const int fq = lane >> 4;
  #pragma unroll
  for (int j = 0; j < MF; ++j) {
    int n = n0 + wn + j * 16 + fr;
    if (n >= g.N) continue;
    float sc = (g.scale ? g.scale[n] : 1.f) * g.alpha;
    float bs = g.bias ? g.bias[n] : 0.f;
    #pragma unroll
    for (int i = 0; i < MF; ++i) {
      int mb = m0 + wm + i * 16 + fq * 4;
      #pragma unroll
      for (int r = 0; r < 4; ++r) {
        int m = mb + r;
        if (m < g.M) {
          float v = acc[i][j][r] * sc + bs;
          if (g.resid) v += g.resid[(long long)b * g.Rbatch + (long long)m * g.Rm + (long long)n * g.Rn];
          if (g.relu) v = fmaxf(v, 0.f);
          g.C[(long long)b * g.Cbatch + (long long)m * g.Cm + (long long)n * g.Cn] = v;
        }
      }
    }
  }
}

// ---------------- weight prep (fp32 -> bf16 hi/lo) ----------------
__global__ void prep_lin_k(const float* __restrict__ src, ushort_t* __restrict__ dh,
                           ushort_t* __restrict__ dl, int tot) {
  int i = blockIdx.x * 256 + threadIdx.x;
  if (i >= tot) return;
  bsplit(src[i], dh[i], dl[i]);
}

// src[n][Cin][KS][KS] -> dst[n][p*ICP+ic], p = ky*KS+kx
__global__ void prep_conv_k(const float* __restrict__ src, ushort_t* __restrict__ dh,
                            ushort_t* __restrict__ dl, int N, int Cin, int ICP, int KS) {
  int idx = blockIdx.x * 256 + threadIdx.x;
  int K2 = KS * KS;
  int tot = N * K2 * ICP;
  if (idx >= tot) return;
  int ic = idx % ICP;
  int p = (idx / ICP) % K2;
  int n = idx / (ICP * K2);
  float v = (ic < Cin) ? src[(n * Cin + ic) * K2 + p] : 0.f;
  bsplit(v, dh[idx], dl[idx]);
}

// src[Cin][Cout][3][3] -> dst[o][p*Cin+ic] with spatial flip
__global__ void prep_convt_k(const float* __restrict__ src, ushort_t* __restrict__ dh,
                             ushort_t* __restrict__ dl, int Cin, int Cout) {
  int idx = blockIdx.x * 256 + threadIdx.x;
  int tot = Cout * 9 * Cin;
  if (idx >= tot) return;
  int ic = idx % Cin;
  int p = (idx / Cin) % 9;
  int o = idx / (9 * Cin);
  int ky = p / 3, kx = p % 3;
  float v = src[((ic * Cout + o) * 3 + (2 - ky)) * 3 + (2 - kx)];
  bsplit(v, dh[idx], dl[idx]);
}

// ---------------- spectral norm -> z ----------------
__global__ __launch_bounds__(256) void spectral_z_k(const float* __restrict__ cond,
    const float* __restrict__ W, const float* __restrict__ u0, float* __restrict__ z) {
  __shared__ float v0[512];
  __shared__ float lds[256];
  __shared__ float wv[16];
  __shared__ float invs[2];
  int tid = threadIdx.x;
  float part = 0.f;
  #pragma unroll
  for (int r = 0; r < 2; ++r) {
    int j = tid + r * 256;
    float s = 0.f;
    #pragma unroll
    for (int i = 0; i < 16; ++i) s = fmaf(W[i * 512 + j], u0[i], s);
    v0[j] = s;
    part = fmaf(s, s, part);
  }
  float nv2 = blk_reduce_sum(part, lds);
  if (tid == 0) invs[0] = 1.f / (sqrtf(nv2) + 1e-12f);
  __syncthreads();
  float inv_nv = invs[0];
  {
    int i = tid >> 4, l = tid & 15;
    float s = 0.f;
    for (int jj = 0; jj < 32; ++jj) {
      int j = l + jj * 16;
      s = fmaf(W[i * 512 + j], v0[j], s);
    }
    lds[tid] = s; __syncthreads();
    if (l == 0) {
      float t = 0.f;
      for (int q = 0; q < 16; ++q) t += lds[(i << 4) + q];
      wv[i] = t * inv_nv;
    }
    __syncthreads();
    if (tid == 0) {
      float s2 = 0.f;
      for (int i2 = 0; i2 < 16; ++i2) s2 = fmaf(wv[i2], wv[i2], s2);
      float nw = sqrtf(s2);
      float sigma = s2 / (nw + 1e-12f);
      invs[1] = 1.f / sigma;
    }
    __syncthreads();
  }
  if (tid < 64) {
    int b = tid >> 4, i = tid & 15;
    float s = 0.f;
    for (int j = 0; j < 512; ++j) s = fmaf(cond[b * 512 + j], W[i * 512 + j], s);
    z[b * 16 + i] = s * invs[1];
  }
}

// ---------------- group norm (32 groups) ----------------
__global__ __launch_bounds__(256) void groupnorm_k(const float* __restrict__ x, float* __restrict__ out,
    const float* __restrict__ gam, const float* __restrict__ bet, int C, int HW, int cpg) {
  __shared__ float lds[256];
  int b = blockIdx.y, grp = blockIdx.x;
  long long base = ((long long)b * C + (long long)grp * cpg) * HW;
  int n = cpg * HW;
  float s = 0.f, s2 = 0.f;
  for (int i = threadIdx.x; i < n; i += 256) { float v = x[base + i]; s += v; s2 = fmaf(v, v, s2); }
  s  = blk_reduce_sum(s, lds);
  s2 = blk_reduce_sum(s2, lds);
  float m = s / (float)n;
  float var = s2 / (float)n - m * m;
  float rinv = 1.f / sqrtf(var + 1e-6f);
  for (int i = threadIdx.x; i < n; i += 256) {
    int c = grp * cpg + i / HW;
    out[base + i] = (x[base + i] - m) * rinv * gam[c] + bet[c];
  }
}

// ---------------- layer norm (dim 256, one token/block) ----------------
__global__ __launch_bounds__(256) void layernorm_k(const float* __restrict__ x, float* __restrict__ out,
    const float* __restrict__ g, const float* __restrict__ b) {
  __shared__ float lds[256];
  long long t = blockIdx.x;
  float v = x[t * 256 + threadIdx.x];
  float s  = blk_reduce_sum(v, lds);
  float s2 = blk_reduce_sum(v * v, lds);
  float m = s * (1.f / 256.f);
  float var = s2 * (1.f / 256.f) - m * m;
  float rinv = 1.f / sqrtf(var + 1e-5f);
  out[t * 256 + threadIdx.x] = (v - m) * rinv * g[threadIdx.x] + b[threadIdx.x];
}

// ---------------- row softmax ----------------
__global__ __launch_bounds__(256) void softmax_k(float* __restrict__ S, int n) {
  __shared__ float lds[256];
  float* p = S + (long long)blockIdx.x * n;
  float mx = -3.4e38f;
  for (int i = threadIdx.x; i < n; i += 256) mx = fmaxf(mx, p[i]);
  mx = blk_reduce_max(mx, lds);
  float s = 0.f;
  for (int i = threadIdx.x; i < n; i += 256) { float e = __expf(p[i] - mx); p[i] = e; s += e; }
  s = blk_reduce_sum(s, lds);
  float inv = 1.f / s;
  for (int i = threadIdx.x; i < n; i += 256) p[i] *= inv;
}

// ---------------- GEGLU ----------------
__global__ void geglu_k(float* __restrict__ p, int ntok) {
  int idx = blockIdx.x * 256 + threadIdx.x;
  if (idx >= ntok * 1024) return;
  int t = idx >> 10, j = idx & 1023;
  float a  = p[t * 2048 + j];
  float gt = p[t * 2048 + 1024 + j];
  float ge = 0.5f * gt * (1.f + erff(gt * 0.70710678118654752f));
  p[t * 2048 + j] = a * ge;
}

// ---------------- degenerate cross-attn ----------------
__global__ __launch_bounds__(256) void crossattn_vec_k(const float* __restrict__ cond,
    const float* __restrict__ v2w, const float* __restrict__ o2w, const float* __restrict__ o2b,
    float* __restrict__ o2buf) {
  __shared__ float kv[256];
  int b = blockIdx.x, oc = threadIdx.x;
  float s = 0.f;
  for (int j = 0; j < 512; ++j) s = fmaf(cond[b * 512 + j], v2w[oc * 512 + j], s);
  kv[oc] = s; __syncthreads();
  float o = o2b[oc];
  for (int ic = 0; ic < 256; ++ic) o = fmaf(kv[ic], o2w[oc * 256 + ic], o);
  o2buf[b * 256 + oc] = o;
}
__global__ void bcast_add_k(float* __restrict__ T, const float* __restrict__ o2buf, int ntok_per_b) {
  long long idx = (long long)blockIdx.x * 256 + threadIdx.x;
  int c = (int)(idx & 255);
  long long tb = idx >> 8;
  int b = (int)(tb / ntok_per_b);
  T[idx] += o2buf[b * 256 + c];
}

// ---------------- final 7x7 conv + tanh ----------------
__global__ __launch_bounds__(256) void conv_final_k(const float* __restrict__ in,
    const float* __restrict__ w, const float* __restrict__ bias, float* __restrict__ out) {
  __shared__ float wl[3 * 64 * 49];
  for (int i = threadIdx.x; i < 3 * 64 * 49; i += 256) wl[i] = w[i];
  __syncthreads();
  int b = blockIdx.y;
  int p = blockIdx.x * 256 + threadIdx.x;
  int y = p / 224, x = p % 224;
  int iy[7], ix[7];
  #pragma unroll
  for (int t = 0; t < 7; ++t) {
    int a = y + t - 3; iy[t] = (a < 0) ? -a : ((a >= 224) ? 446 - a : a);
    int c = x + t - 3; ix[t] = (c < 0) ? -c : ((c >= 224) ? 446 - c : c);
  }
  float a0 = bias[0], a1 = bias[1], a2 = bias[2];
  for (int ic = 0; ic < 64; ++ic) {
    const float* ip = in + (long long)(b * 64 + ic) * N224;
    const float* w0 = &wl[(0 * 64 + ic) * 49];
    const float* w1 = &wl[(1 * 64 + ic) * 49];
    const float* w2 = &wl[(2 * 64 + ic) * 49];
    #pragma unroll
    for (int ky = 0; ky < 7; ++ky) {
      const float* rp = ip + iy[ky] * 224;
      #pragma unroll
      for (int kx = 0; kx < 7; ++kx) {
        float v = rp[ix[kx]];
        int t = ky * 7 + kx;
        a0 = fmaf(v, w0[t], a0);
        a1 = fmaf(v, w1[t], a1);
        a2 = fmaf(v, w2[t], a2);
      }
    }
  }
  long long ob = (long long)b * 3 * N224 + p;
  out[ob]            = tanhf(a0);
  out[ob + N224]     = tanhf(a1);
  out[ob + 2 * N224] = tanhf(a2);
}

// ---------------- gaussian blur * eps ----------------
__global__ void blur_k(const float* __restrict__ x, float* __restrict__ out, const int* __restrict__ epsp) {
  int idx = blockIdx.x * 256 + threadIdx.x;
  int xp = idx % 224;
  int y  = (idx / 224) % 224;
  int bc = idx / N224;
  const float* p = x + (long long)bc * N224;
  const float kc = 0.20417996f, k1 = 0.12384140f, k2 = 0.07511360f;
  float s = 0.f;
  #pragma unroll
  for (int dy = -1; dy <= 1; ++dy) {
    int yy = y + dy;
    if (yy < 0 || yy >= 224) continue;
    #pragma unroll
    for (int dx = -1; dx <= 1; ++dx) {
      int xx = xp + dx;
      if (xx < 0 || xx >= 224) continue;
      float wgt = (dy == 0 && dx == 0) ? kc : ((dy != 0 && dx != 0) ? k2 : k1);
      s = fmaf(p[yy * 224 + xx], wgt, s);
    }
  }
  out[idx] = s * (float)epsp[0];
}

// ---------------- host ----------------
static inline MArgs MA() { MArgs g = {}; g.alpha = 1.f; return g; }

template<int AMODE, int TILE, int BSPLIT>
static inline void mgl(hipStream_t s, const MArgs& g, int zb) {
  constexpr int Bt = TILE ? 64 : 128;
  dim3 grid(DIVUP(g.N, Bt), DIVUP(g.M, Bt), zb);
  mg_k<AMODE, TILE, BSPLIT><<<grid, 256, 0, s>>>(g);
}

extern "C" void kernel_launch(void* const* d_in, const int* in_sizes, int n_in,
                              void* d_out, int out_size, void* d_ws, size_t ws_size,
                              hipStream_t stream) {
  (void)in_sizes; (void)n_in; (void)out_size; (void)ws_size;
  const float* input = (const float*)d_in[0];
  const float* cond  = (const float*)d_in[1];
  const float* sn_w  = (const float*)d_in[2];
  const float* sn_u  = (const float*)d_in[3];
  const float* c1_w  = (const float*)d_in[4];
  const float* bn1_g = (const float*)d_in[5];
  const float* bn1_b = (const float*)d_in[6];
  const float* c2_w  = (const float*)d_in[7];
  const float* bn2_g = (const float*)d_in[8];
  const float* bn2_b = (const float*)d_in[9];
  const float* c3_w  = (const float*)d_in[10];
  const float* bn3_g = (const float*)d_in[11];
  const float* bn3_b = (const float*)d_in[12];
  const float* res_w = (const float*)d_in[13];
  const float* res_g = (const float*)d_in[14];
  const float* res_b = (const float*)d_in[15];
  const float* gn_g  = (const float*)d_in[16];
  const float* gn_b  = (const float*)d_in[17];
  const float* pin_w = (const float*)d_in[18];
  const float* pin_b = (const float*)d_in[19];
  const float* q1w   = (const float*)d_in[20];
  const float* k1w   = (const float*)d_in[21];
  const float* v1w   = (const float*)d_in[22];
  const float* o1w   = (const float*)d_in[23];
  const float* o1b   = (const float*)d_in[24];
  /* 25 st_q2, 26 st_k2: dead (ctx length 1 -> softmax == 1) */
  const float* v2w   = (const float*)d_in[27];
  const float* o2w   = (const float*)d_in[28];
  const float* o2b   = (const float*)d_in[29];
  const float* ffpw  = (const float*)d_in[30];
  const float* ffpb  = (const float*)d_in[31];
  const float* ffow  = (const float*)d_in[32];
  const float* ffob  = (const float*)d_in[33];
  const float* ln1g  = (const float*)d_in[34];
  const float* ln1b  = (const float*)d_in[35];
  /* 36,37: ln2 dead */
  const float* ln3g  = (const float*)d_in[38];
  const float* ln3b  = (const float*)d_in[39];
  const float* poutw = (const float*)d_in[40];
  const float* poutb = (const float*)d_in[41];
  const float* up1w  = (const float*)d_in[42];
  const float* up1g  = (const float*)d_in[43];
  const float* up1b  = (const float*)d_in[44];
  const float* up2w  = (const float*)d_in[45];
  const float* up2g  = (const float*)d_in[46];
  const float* up2b  = (const float*)d_in[47];
  const float* cfw   = (const float*)d_in[48];
  const float* cfb   = (const float*)d_in[49];
  const int*   epsp  = (const int*)d_in[50];

  const long long S56 = (long long)C4 * N56;      // 802816

  // ---- workspace layout (~203 MB, with aliasing) ----
  float* A1   = (float*)d_ws;                      // 12,845,056 f  (4x64x224x224)
  float* A2   = A1 + 12845056;                     //  6,422,528 f  (4x128x112x112)
  float* SIMb = A2 + 6422528;                      //  9,834,496 f  (3136^2)
  float* X    = SIMb + 9834496;                    //  3,211,264 f
  float* T    = X + 3211264;
  float* Hb   = T + 3211264;                       // also AO (PV out)
  float* Qb   = Hb + 3211264;
  float* Kb   = Qb + 3211264;
  float* Vt   = Kb + 3211264;                      // V transposed (ch-major)
  ushort_t* TFWh = (ushort_t*)(Vt + 3211264);      // 2,359,296 us
  ushort_t* TFWl = TFWh + 2359296;
  float* Zb = (float*)(TFWl + 2359296);            // 64 f
  float* O2 = Zb + 64;                             // 1024 f
  // overlays:
  ushort_t* RESW = (ushort_t*)A1;                  // res conv weights, live c2..res5
  ushort_t* SC = (ushort_t*)SIMb;                  // small conv weights (SIMb overlay!)
  ushort_t* c1h = SC,            * c1l = c1h + 100352;   // live: before transformer(0)
  ushort_t* c2h = c1l + 100352,  * c2l = c2h + 110592;
  ushort_t* c3h = c2l + 110592,  * c3l = c3h + 368640;
  ushort_t* u1h = c3l + 368640,  * u1l = u1h + 294912;   // prepped AFTER transformers (SIM clobbers SC)
  ushort_t* u2h = u1l + 294912,  * u2l = u2h + 73728;
  float* CF = SIMb + 948224;                       // 602,112 f, final phase only (after SC block)
  float* FF = A2;                                  // per-batch FF buffer (exact alias)

  // per-tf split-weight offsets (elements)
  const int TFQ = 0, TFK = 65536, TFV = 131072, TFO1 = 196608, TFPIN = 262144,
            TFPOUT = 327680, TFFFP = 393216, TFFFO = 917504, TFSZ = 1179648;

  // ---- 1) z + weight prep ----
  spectral_z_k<<<1, 256, 0, stream>>>(cond, sn_w, sn_u, Zb);
  prep_conv_k<<<DIVUP(64 * 49 * 32, 256), 256, 0, stream>>>(c1_w, c1h, c1l, 64, 19, 32, 7);
  prep_conv_k<<<DIVUP(128 * 9 * 96, 256), 256, 0, stream>>>(c2_w, c2h, c2l, 128, 80, 96, 3);
  prep_conv_k<<<DIVUP(256 * 9 * 160, 256), 256, 0, stream>>>(c3_w, c3h, c3l, 256, 144, 160, 3);
  for (int i = 0; i < 2; ++i) {
    ushort_t* bh = TFWh + i * TFSZ; ushort_t* bl = TFWl + i * TFSZ;
    prep_lin_k<<<256, 256, 0, stream>>>(q1w  + (size_t)i * 65536, bh + TFQ,   bl + TFQ,   65536);
    prep_lin_k<<<256, 256, 0, stream>>>(k1w  + (size_t)i * 65536, bh + TFK,   bl + TFK,   65536);
    prep_lin_k<<<256, 256, 0, stream>>>(v1w  + (size_t)i * 65536, bh + TFV,   bl + TFV,   65536);
    prep_lin_k<<<256, 256, 0, stream>>>(o1w  + (size_t)i * 65536, bh + TFO1,  bl + TFO1,  65536);
    prep_lin_k<<<256, 256, 0, stream>>>(pin_w + (size_t)i * 65536, bh + TFPIN, bl + TFPIN, 65536);
    prep_lin_k<<<256, 256, 0, stream>>>(poutw + (size_t)i * 65536, bh + TFPOUT, bl + TFPOUT, 65536);
    prep_lin_k<<<2048, 256, 0, stream>>>(ffpw + (size_t)i * 524288, bh + TFFFP, bl + TFFFP, 524288);
    prep_lin_k<<<1024, 256, 0, stream>>>(ffow + (size_t)i * 262144, bh + TFFFO, bl + TFFFO, 262144);
  }

  // ---- 2) c1: 7x7 reflect(3), (3+16z)->64, BN+ReLU ----
  {
    MArgs g = MA();
    g.Xp = input; g.Xbatch = 3LL * N224; g.z = Zb; g.Cin = 3;
    g.Bh = c1h; g.Bl = c1l; g.Bstride = 1568;
    g.C = A1; g.Cm = 1; g.Cn = N224; g.Cbatch = 64LL * N224;
    g.scale = bn1_g; g.bias = bn1_b; g.alpha = BN_ALPHA; g.relu = 1;
    g.M = N224; g.N = 64; g.ICP = 32; g.NPH = 49;
    g.KS = 7; g.Hin = 224; g.Win = 224; g.Wout = 224; g.stride = 1; g.pad = 3; g.reflect = 1;
    mgl<1, 0, 1>(stream, g, BB);
  }
  // ---- 3) c2: 3x3 s2, (64+16z)->128 ----
  {
    MArgs g = MA();
    g.Xp = A1; g.Xbatch = 64LL * N224; g.z = Zb; g.Cin = 64;
    g.Bh = c2h; g.Bl = c2l; g.Bstride = 864;
    g.C = A2; g.Cm = 1; g.Cn = N112; g.Cbatch = 128LL * N112;
    g.scale = bn2_g; g.bias = bn2_b; g.alpha = BN_ALPHA; g.relu = 1;
    g.M = N112; g.N = 128; g.ICP = 96; g.NPH = 9;
    g.KS = 3; g.Hin = 224; g.Win = 224; g.Wout = 112; g.stride = 2; g.pad = 1; g.reflect = 0;
    mgl<1, 0, 1>(stream, g, BB);
  }
  // ---- prep resblock weights into A1 overlay (A1 activations dead after c2) ----
  for (int j = 0; j < 12; ++j) {
    ushort_t* bh = RESW + (size_t)j * 1179648;
    prep_conv_k<<<DIVUP(256 * 9 * 256, 256), 256, 0, stream>>>(
        res_w + (size_t)j * 589824, bh, bh + 589824, 256, 256, 256, 3);
  }
  // ---- 4) c3: 3x3 s2, (128+16z)->256 ----
  {
    MArgs g = MA();
    g.Xp = A2; g.Xbatch = 128LL * N112; g.z = Zb; g.Cin = 128;
    g.Bh = c3h; g.Bl = c3l; g.Bstride = 1440;
    g.C = X; g.Cm = 1; g.Cn = N56; g.Cbatch = S56;
    g.scale = bn3_g; g.bias = bn3_b; g.alpha = BN_ALPHA; g.relu = 1;
    g.M = N56; g.N = 256; g.ICP = 160; g.NPH = 9;
    g.KS = 3; g.Hin = 112; g.Win = 112; g.Wout = 56; g.stride = 2; g.pad = 1; g.reflect = 0;
    mgl<1, 0, 1>(stream, g, BB);
  }

  auto resconv = [&](int j, const float* src, float* dst, int relu, const float* resid) {
    MArgs g = MA();
    g.Xp = src; g.Xbatch = S56; g.Cin = 256;
    ushort_t* bh = RESW + (size_t)j * 1179648;
    g.Bh = bh; g.Bl = bh + 589824; g.Bstride = 2304;
    g.C = dst; g.Cm = 1; g.Cn = N56; g.Cbatch = S56;
    g.scale = res_g + j * 256; g.bias = res_b + j * 256; g.alpha = BN_ALPHA; g.relu = relu;
    if (resid) { g.resid = resid; g.Rm = 1; g.Rn = N56; g.Rbatch = S56; }
    g.M = N56; g.N = 256; g.ICP = 256; g.NPH = 9;
    g.KS = 3; g.Hin = 56; g.Win = 56; g.Wout = 56; g.stride = 1; g.pad = 1; g.reflect = 1;
    mgl<1, 0, 1>(stream, g, BB);
  };
  auto resblock = [&](int r) {
    resconv(r * 2, X, Hb, 1, nullptr);
    resconv(r * 2 + 1, Hb, X, 0, X);
  };

  auto lin = [&](int i, int woff, const float* A, long long Am, long long Ak, long long Ab,
                 float* C, long long Cm, long long Cn, long long Cb,
                 const float* bias, const float* resid, long long Rm, long long Rn, long long Rb,
                 int M, int N, int K, float alpha, int tile, int zb) {
    MArgs g = MA();
    g.A = A; g.Am = Am; g.Ak = Ak; g.Abatch = Ab;
    g.Bh = TFWh + i * TFSZ + woff; g.Bl = TFWl + i * TFSZ + woff; g.Bstride = K;
    g.C = C; g.Cm = Cm; g.Cn = Cn; g.Cbatch = Cb;
    g.bias = bias;
    if (resid) { g.resid = resid; g.Rm = Rm; g.Rn = Rn; g.Rbatch = Rb; }
    g.alpha = alpha; g.M = M; g.N = N; g.ICP = K; g.NPH = 1;
    if (tile) mgl<0, 1, 1>(stream, g, zb); else mgl<0, 0, 1>(stream, g, zb);
  };

  auto transformer = [&](int i) {
    groupnorm_k<<<dim3(32, BB), 256, 0, stream>>>(X, Hb, gn_g + i * 256, gn_b + i * 256, 256, N56, 8);
    // proj_in: A = GN out (ch-major), C = tokens T
    lin(i, TFPIN, Hb, 1, N56, S56, T, 256, 1, S56, pin_b + i * 256,
        nullptr, 0, 0, 0, N56, 256, 256, 1.f, 1, BB);
    layernorm_k<<<BB * N56, 256, 0, stream>>>(T, Hb, ln1g + i * 256, ln1b + i * 256);
    // Q,K token-major; V channel-major
    lin(i, TFQ, Hb, 256, 1, S56, Qb, 256, 1, S56, nullptr, nullptr, 0, 0, 0, N56, 256, 256, 1.f, 1, BB);
    lin(i, TFK, Hb, 256, 1, S56, Kb, 256, 1, S56, nullptr, nullptr, 0, 0, 0, N56, 256, 256, 1.f, 1, BB);
    lin(i, TFV, Hb, 256, 1, S56, Vt, 1, N56, S56, nullptr, nullptr, 0, 0, 0, N56, 256, 256, 1.f, 1, BB);
    for (int b = 0; b < BB; ++b) {
      {  // QK^T
        MArgs g = MA();
        g.A = Qb + (size_t)b * S56; g.Am = 256; g.Ak = 1; g.Abatch = 0;
        g.Bf = Kb + (size_t)b * S56; g.Bstride = 256; g.Bbatch = 0;
        g.C = SIMb; g.Cm = N56; g.Cn = 1; g.Cbatch = 0;
        g.alpha = 0.0625f; g.M = N56; g.N = N56; g.ICP = 256; g.NPH = 1;
        mgl<0, 0, 0>(stream, g, 1);
      }
      softmax_k<<<N56, 256, 0, stream>>>(SIMb, N56);
      {  // PV: B = Vt (ch-major, k-fast)
        MArgs g = MA();
        g.A = SIMb; g.Am = N56; g.Ak = 1; g.Abatch = 0;
        g.Bf = Vt + (size_t)b * S56; g.Bstride = N56; g.Bbatch = 0;
        g.C = Hb + (size_t)b * S56; g.Cm = 256; g.Cn = 1; g.Cbatch = 0;
        g.M = N56; g.N = 256; g.ICP = N56; g.NPH = 1;
        mgl<0, 1, 0>(stream, g, 1);
      }
    }
    // out proj + residual into T (A = Hb, which holds AO)
    lin(i, TFO1, Hb, 256, 1, S56, T, 256, 1, S56, o1b + i * 256,
        T, 256, 1, S56, N56, 256, 256, 1.f, 1, BB);
    crossattn_vec_k<<<BB, 256, 0, stream>>>(cond, v2w + (size_t)i * 131072,
                                            o2w + (size_t)i * 65536, o2b + i * 256, O2);
    bcast_add_k<<<BB * N56, 256, 0, stream>>>(T, O2, N56);
    layernorm_k<<<BB * N56, 256, 0, stream>>>(T, Hb, ln3g + i * 256, ln3b + i * 256);
    for (int b = 0; b < BB; ++b) {
      lin(i, TFFFP, Hb + (size_t)b * S56, 256, 1, 0, FF, 2048, 1, 0, ffpb + i * 2048,
          nullptr, 0, 0, 0, N56, 2048, 256, 1.f, 0, 1);
      geglu_k<<<DIVUP(N56 * 1024, 256), 256, 0, stream>>>(FF, N56);
      lin(i, TFFFO, FF, 2048, 1, 0, T + (size_t)b * S56, 256, 1, 0, ffob + i * 256,
          T + (size_t)b * S56, 256, 1, 0, N56, 256, 1024, 1.f, 1, 1);
    }
    // proj_out: tokens -> NCHW + residual X
    lin(i, TFPOUT, T, 256, 1, S56, X, 1, N56, S56, poutb + i * 256,
        X, 1, N56, S56, N56, 256, 256, 1.f, 1, BB);
  };

  resblock(0); resblock(1);
  transformer(0);
  resblock(2); resblock(3);
  transformer(1);
  resblock(4); resblock(5);

  // ---- prep convT weights NOW (SC overlay of SIMb was clobbered by attention SIM) ----
  prep_convt_k<<<DIVUP(128 * 9 * 256, 256), 256, 0, stream>>>(up1w, u1h, u1l, 256, 128);
  prep_convt_k<<<DIVUP(64 * 9 * 128, 256), 256, 0, stream>>>(up2w, u2h, u2l, 128, 64);

  // ---- up1: convT 256->128, 56->112 ----
  {
    MArgs g = MA();
    g.Xp = X; g.Xbatch = S56; g.Cin = 256;
    g.Bh = u1h; g.Bl = u1l; g.Bstride = 2304;
    g.C = A2; g.Cm = 1; g.Cn = N112; g.Cbatch = 128LL * N112;
    g.scale = up1g; g.bias = up1b; g.alpha = BN_ALPHA; g.relu = 1;
    g.M = N112; g.N = 128; g.ICP = 256; g.NPH = 9;
    g.KS = 3; g.Hin = 56; g.Win = 56; g.Wout = 112;
    mgl<2, 0, 1>(stream, g, BB);
  }
  // ---- up2: convT 128->64, 112->224 ----
  {
    MArgs g = MA();
    g.Xp = A2; g.Xbatch = 128LL * N112; g.Cin = 128;
    g.Bh = u2h; g.Bl = u2l; g.Bstride = 1152;
    g.C = A1; g.Cm = 1; g.Cn = N224; g.Cbatch = 64LL * N224;
    g.scale = up2g; g.bias = up2b; g.alpha = BN_ALPHA; g.relu = 1;
    g.M = N224; g.N = 64; g.ICP = 128; g.NPH = 9;
    g.KS = 3; g.Hin = 112; g.Win = 112; g.Wout = 224;
    mgl<2, 0, 1>(stream, g, BB);
  }

  conv_final_k<<<dim3(N224 / 256, BB), 256, 0, stream>>>(A1, cfw, cfb, CF);
  blur_k<<<DIVUP(BB * 3 * N224, 256), 256, 0, stream>>>(CF, (float*)d_out, epsp);
}

// Round 5
// 8740.561 us; speedup vs baseline: 2.2028x; 1.2612x over previous
//
#include <hip/hip_runtime.h>
#include <math.h>

#ifndef DIVUP
#define DIVUP(a,b) (((a)+(b)-1)/(b))
#endif

typedef unsigned short ushort_t;
typedef __attribute__((ext_vector_type(8))) short v8s;
typedef __attribute__((ext_vector_type(4))) float v4f;

#define BB 4
#define NZ 16
#define C4 256
#define N56 3136
#define N112 12544
#define N224 50176

static const float BN_ALPHA = 0.99999500003749967f;  // 1/sqrt(1+1e-5)

// ---------------- helpers ----------------
__device__ inline int refl_idx(int i, int n) {
  if (i < 0) i = -i;
  if (i >= n) i = 2 * n - 2 - i;
  return i;
}

// RNE split: v ~= hi + lo (both bf16)
__device__ inline void bsplit(float v, ushort_t& h, ushort_t& l) {
  unsigned b = __float_as_uint(v);
  unsigned r = (b + 0x7FFFu + ((b >> 16) & 1u)) & 0xFFFF0000u;
  h = (ushort_t)(r >> 16);
  float lo = v - __uint_as_float(r);
  unsigned bl_ = __float_as_uint(lo);
  unsigned rl = bl_ + 0x7FFFu + ((bl_ >> 16) & 1u);
  l = (ushort_t)(rl >> 16);
}

__device__ inline float blk_reduce_sum(float v, float* lds) {
  int t = threadIdx.x;
  lds[t] = v; __syncthreads();
  for (int s = 128; s > 0; s >>= 1) { if (t < s) lds[t] += lds[t + s]; __syncthreads(); }
  float r = lds[0]; __syncthreads();
  return r;
}
__device__ inline float blk_reduce_max(float v, float* lds) {
  int t = threadIdx.x;
  lds[t] = v; __syncthreads();
  for (int s = 128; s > 0; s >>= 1) { if (t < s) lds[t] = fmaxf(lds[t], lds[t + s]); __syncthreads(); }
  float r = lds[0]; __syncthreads();
  return r;
}

// ---------------- MFMA GEMM ----------------
// C[b][m][n] = act( alpha*scale[n] * sum_k A[m][k]*W[n][k] + bias[n] + resid )
// AMODE: 0 strided A; 1 implicit im2col conv (phase-major K, +z); 2 implicit convT
// BSPLIT: 1 = B pre-split ushort hi/lo; 0 = B fp32 (split inline)
// KSTEP in {32,64}; conv modes require ICP % KSTEP == 0.
struct MArgs {
  const float* A; long long Am, Ak, Abatch;          // AMODE 0
  const float* Xp; long long Xbatch;                 // AMODE 1/2 (NCHW input)
  const float* z;                                    // appended channels (AMODE 1)
  const ushort_t* Bh; const ushort_t* Bl;            // BSPLIT=1
  const float* Bf; long long Bbatch;                 // BSPLIT=0
  long long Bstride;                                 // row length (= padded K)
  float* C; long long Cm, Cn, Cbatch;
  const float* scale; const float* bias;
  const float* resid; long long Rm, Rn, Rbatch;
  float alpha; int relu;
  int M, N;
  int ICP, NPH;                                      // K = ICP*NPH (mult of KSTEP)
  int Cin;                                           // real channels (conv)
  int KS, Hin, Win, Wout, stride, pad, reflect;
};

template<int AMODE, int BMN, int KSTEP, int BSPLIT>
__global__ __launch_bounds__(256, (BMN == 64 ? 3 : 2)) void mg_k(MArgs g) {
  constexpr int EPT  = BMN * KSTEP / 256;  // k-elems per thread per operand
  constexpr int MF   = BMN / 32;           // 16x16 frags per wave per dim
  constexpr int LDSW = KSTEP + 8;          // padded row (ushorts), pitch 16B-aligned
  constexpr int NSUB = KSTEP / 32;
  __shared__ __align__(16) ushort_t sAh[BMN * LDSW];
  __shared__ __align__(16) ushort_t sAl[BMN * LDSW];
  __shared__ __align__(16) ushort_t sBh[BMN * LDSW];
  __shared__ __align__(16) ushort_t sBl[BMN * LDSW];

  const int tid = threadIdx.x;
  const int b = blockIdx.z;
  const int m0 = blockIdx.y * BMN, n0 = blockIdx.x * BMN;
  const int lane = tid & 63, w = tid >> 6;
  const int wm = (w >> 1) * (MF * 16), wn = (w & 1) * (MF * 16);

  const int srow = tid & (BMN - 1);
  const int skoff = (tid / BMN) * EPT;

  // ---- A setup ----
  int am = m0 + srow; if (am >= g.M) am = g.M - 1;
  int cy = 0, cx = 0;
  const float* Aptr;
  if (AMODE == 0) {
    Aptr = g.A + (long long)b * g.Abatch + (long long)am * g.Am;
  } else {
    cy = am / g.Wout; cx = am - cy * g.Wout;
    Aptr = g.Xp + (long long)b * g.Xbatch;
  }
  const int HW = g.Hin * g.Win;

  // ---- B setup ----
  int bn = n0 + srow; if (bn >= g.N) bn = g.N - 1;
  const ushort_t* BhP = BSPLIT ? (g.Bh + (long long)bn * g.Bstride + skoff) : nullptr;
  const ushort_t* BlP = BSPLIT ? (g.Bl + (long long)bn * g.Bstride + skoff) : nullptr;
  const float* BfP = BSPLIT ? nullptr : (g.Bf + (long long)b * g.Bbatch + (long long)bn * g.Bstride + skoff);

  // phase state (conv modes)
  int ph = 0, ic0 = 0, pbase = 0;
  bool pvalid = true;
  int kglob = 0;

  float areg[EPT];
  ushort_t bregh[EPT], bregl[EPT];
  float bregf[EPT];

  auto fetchA = [&]() {
    if (AMODE == 0) {
      const float* Ap = Aptr + (long long)(kglob + skoff) * g.Ak;
      if (g.Ak == 1) {
        #pragma unroll
        for (int e = 0; e < EPT; ++e) areg[e] = Ap[e];
      } else {
        #pragma unroll
        for (int e = 0; e < EPT; ++e) areg[e] = Ap[(long long)e * g.Ak];
      }
      kglob += KSTEP;
    } else {
      if (ic0 == 0) {
        int ky = ph / g.KS, kx = ph - ky * g.KS;
        if (AMODE == 1) {
          int iy = cy * g.stride + ky - g.pad;
          int ix = cx * g.stride + kx - g.pad;
          if (g.reflect) {
            iy = refl_idx(iy, g.Hin); ix = refl_idx(ix, g.Win); pvalid = true;
          } else {
            pvalid = (iy >= 0 && iy < g.Hin && ix >= 0 && ix < g.Win);
            if (iy < 0) iy = 0; if (iy >= g.Hin) iy = g.Hin - 1;
            if (ix < 0) ix = 0; if (ix >= g.Win) ix = g.Win - 1;
          }
          pbase = iy * g.Win + ix;
        } else {
          int iy2 = cy + ky - 1, ix2 = cx + kx - 1;
          pvalid = (iy2 >= 0) && (ix2 >= 0) && !(iy2 & 1) && !(ix2 & 1);
          int iy = iy2 >> 1, ix = ix2 >> 1;
          if (pvalid && (iy >= g.Hin || ix >= g.Win)) pvalid = false;
          if (!pvalid) { iy = 0; ix = 0; }
          pbase = iy * g.Win + ix;
        }
      }
      #pragma unroll
      for (int e = 0; e < EPT; ++e) {
        int ic = ic0 + skoff + e;
        float v = 0.f;
        if (pvalid) {
          if (ic < g.Cin) v = Aptr[pbase + ic * HW];
          else if (g.z && ic < g.Cin + NZ) v = g.z[b * NZ + (ic - g.Cin)];
        }
        areg[e] = v;
      }
      ic0 += KSTEP; if (ic0 == g.ICP) { ic0 = 0; ++ph; }
    }
  };

  auto fetchB = [&](int k0) {
    if (BSPLIT) {
      #pragma unroll
      for (int e = 0; e < EPT; ++e) { bregh[e] = BhP[k0 + e]; bregl[e] = BlP[k0 + e]; }
    } else {
      #pragma unroll
      for (int e = 0; e < EPT; ++e) bregf[e] = BfP[k0 + e];
    }
  };

  v4f acc[MF][MF];
  #pragma unroll
  for (int i = 0; i < MF; ++i)
    #pragma unroll
    for (int j = 0; j < MF; ++j) acc[i][j] = (v4f)(0.f);

  const int nt = (g.ICP * g.NPH) / KSTEP;
  fetchA(); fetchB(0);

  const int fr = lane & 15, fk = (lane >> 4) * 8;

  for (int t = 0; t < nt; ++t) {
    __syncthreads();
    {
      ushort_t ah[EPT], al[EPT];
      #pragma unroll
      for (int e = 0; e < EPT; ++e) bsplit(areg[e], ah[e], al[e]);
      #pragma unroll
      for (int e = 0; e < EPT; ++e) { sAh[srow * LDSW + skoff + e] = ah[e]; sAl[srow * LDSW + skoff + e] = al[e]; }
      if (BSPLIT) {
        #pragma unroll
        for (int e = 0; e < EPT; ++e) { sBh[srow * LDSW + skoff + e] = bregh[e]; sBl[srow * LDSW + skoff + e] = bregl[e]; }
      } else {
        ushort_t bh[EPT], bl[EPT];
        #pragma unroll
        for (int e = 0; e < EPT; ++e) bsplit(bregf[e], bh[e], bl[e]);
        #pragma unroll
        for (int e = 0; e < EPT; ++e) { sBh[srow * LDSW + skoff + e] = bh[e]; sBl[srow * LDSW + skoff + e] = bl[e]; }
      }
    }
    __syncthreads();
    if (t + 1 < nt) { fetchA(); fetchB((t + 1) * KSTEP); }
    #pragma unroll
    for (int ks = 0; ks < NSUB; ++ks) {
      v8s fah[MF], fal[MF], fbh[MF], fbl[MF];
      #pragma unroll
      for (int i = 0; i < MF; ++i) {
        fah[i] = *(const v8s*)&sAh[(wm + i * 16 + fr) * LDSW + ks * 32 + fk];
        fal[i] = *(const v8s*)&sAl[(wm + i * 16 + fr) * LDSW + ks * 32 + fk];
        fbh[i] = *(const v8s*)&sBh[(wn + i * 16 + fr) * LDSW + ks * 32 + fk];
        fbl[i] = *(const v8s*)&sBl[(wn + i * 16 + fr) * LDSW + ks * 32 + fk];
      }
      #pragma unroll
      for (int i = 0; i < MF; ++i)
        #pragma unroll
        for (int j = 0; j < MF; ++j) {
          acc[i][j] = __builtin_amdgcn_mfma_f32_16x16x32_bf16(fah[i], fbh[j], acc[i][j], 0, 0, 0);
          acc[i][j] = __builtin_amdgcn_mfma_f32_16x16x32_bf16(fah[i], fbl[j], acc[i][j], 0, 0, 0);
          acc[i][j] = __builtin_amdgcn_mfma_f32_16x16x32_bf16(fal[i], fbh[j], acc[i][j], 0, 0, 0);
        }
    }
  }

  // epilogue: C/D layout col=lane&15, row=(lane>>4)*4+reg
  const int fq = lane >> 4;
  #pragma unroll
  for (int j = 0; j < MF; ++j) {
    int n = n0 + wn + j * 16 + fr;
    if (n >= g.N) continue;
    float sc = (g.scale ? g.scale[n] : 1.f) * g.alpha;
    float bs = g.bias ? g.bias[n] : 0.f;
    #pragma unroll
    for (int i = 0; i < MF; ++i) {
      int mb = m0 + wm + i * 16 + fq * 4;
      #pragma unroll
      for (int r = 0; r < 4; ++r) {
        int m = mb + r;
        if (m < g.M) {
          float v = acc[i][j][r] * sc + bs;
          if (g.resid) v += g.resid[(long long)b * g.Rbatch + (long long)m * g.Rm + (long long)n * g.Rn];
          if (g.relu) v = fmaxf(v, 0.f);
          g.C[(long long)b * g.Cbatch + (long long)m * g.Cm + (long long)n * g.Cn] = v;
        }
      }
    }
  }
}

// ---------------- weight prep (fp32 -> bf16 hi/lo) ----------------
__global__ void prep_lin_k(const float* __restrict__ src, ushort_t* __restrict__ dh,
                           ushort_t* __restrict__ dl, int tot) {
  int i = blockIdx.x * 256 + threadIdx.x;
  if (i >= tot) return;
  bsplit(src[i], dh[i], dl[i]);
}

// src[n][Cin][KS][KS] -> dst[n][p*ICP+ic], p = ky*KS+kx
__global__ void prep_conv_k(const float* __restrict__ src, ushort_t* __restrict__ dh,
                            ushort_t* __restrict__ dl, int N, int Cin, int ICP, int KS) {
  int idx = blockIdx.x * 256 + threadIdx.x;
  int K2 = KS * KS;
  int tot = N * K2 * ICP;
  if (idx >= tot) return;
  int ic = idx % ICP;
  int p = (idx / ICP) % K2;
  int n = idx / (ICP * K2);
  float v = (ic < Cin) ? src[(n * Cin + ic) * K2 + p] : 0.f;
  bsplit(v, dh[idx], dl[idx]);
}

// src[Cin][Cout][3][3] -> dst[o][p*Cin+ic] with spatial flip
__global__ void prep_convt_k(const float* __restrict__ src, ushort_t* __restrict__ dh,
                             ushort_t* __restrict__ dl, int Cin, int Cout) {
  int idx = blockIdx.x * 256 + threadIdx.x;
  int tot = Cout * 9 * Cin;
  if (idx >= tot) return;
  int ic = idx % Cin;
  int p = (idx / Cin) % 9;
  int o = idx / (9 * Cin);
  int ky = p / 3, kx = p % 3;
  float v = src[((ic * Cout + o) * 3 + (2 - ky)) * 3 + (2 - kx)];
  bsplit(v, dh[idx], dl[idx]);
}

// ---------------- spectral norm -> z ----------------
__global__ __launch_bounds__(256) void spectral_z_k(const float* __restrict__ cond,
    const float* __restrict__ W, const float* __restrict__ u0, float* __restrict__ z) {
  __shared__ float v0[512];
  __shared__ float lds[256];
  __shared__ float wv[16];
  __shared__ float invs[2];
  int tid = threadIdx.x;
  float part = 0.f;
  #pragma unroll
  for (int r = 0; r < 2; ++r) {
    int j = tid + r * 256;
    float s = 0.f;
    #pragma unroll
    for (int i = 0; i < 16; ++i) s = fmaf(W[i * 512 + j], u0[i], s);
    v0[j] = s;
    part = fmaf(s, s, part);
  }
  float nv2 = blk_reduce_sum(part, lds);
  if (tid == 0) invs[0] = 1.f / (sqrtf(nv2) + 1e-12f);
  __syncthreads();
  float inv_nv = invs[0];
  {
    int i = tid >> 4, l = tid & 15;
    float s = 0.f;
    for (int jj = 0; jj < 32; ++jj) {
      int j = l + jj * 16;
      s = fmaf(W[i * 512 + j], v0[j], s);
    }
    lds[tid] = s; __syncthreads();
    if (l == 0) {
      float t = 0.f;
      for (int q = 0; q < 16; ++q) t += lds[(i << 4) + q];
      wv[i] = t * inv_nv;
    }
    __syncthreads();
    if (tid == 0) {
      float s2 = 0.f;
      for (int i2 = 0; i2 < 16; ++i2) s2 = fmaf(wv[i2], wv[i2], s2);
      float nw = sqrtf(s2);
      float sigma = s2 / (nw + 1e-12f);
      invs[1] = 1.f / sigma;
    }
    __syncthreads();
  }
  if (tid < 64) {
    int b = tid >> 4, i = tid & 15;
    float s = 0.f;
    for (int j = 0; j < 512; ++j) s = fmaf(cond[b * 512 + j], W[i * 512 + j], s);
    z[b * 16 + i] = s * invs[1];
  }
}

// ---------------- group norm (32 groups) ----------------
__global__ __launch_bounds__(256) void groupnorm_k(const float* __restrict__ x, float* __restrict__ out,
    const float* __restrict__ gam, const float* __restrict__ bet, int C, int HW, int cpg) {
  __shared__ float lds[256];
  int b = blockIdx.y, grp = blockIdx.x;
  long long base = ((long long)b * C + (long long)grp * cpg) * HW;
  int n = cpg * HW;
  float s = 0.f, s2 = 0.f;
  for (int i = threadIdx.x; i < n; i += 256) { float v = x[base + i]; s += v; s2 = fmaf(v, v, s2); }
  s  = blk_reduce_sum(s, lds);
  s2 = blk_reduce_sum(s2, lds);
  float m = s / (float)n;
  float var = s2 / (float)n - m * m;
  float rinv = 1.f / sqrtf(var + 1e-6f);
  for (int i = threadIdx.x; i < n; i += 256) {
    int c = grp * cpg + i / HW;
    out[base + i] = (x[base + i] - m) * rinv * gam[c] + bet[c];
  }
}

// ---------------- layer norm (dim 256, one token/block) ----------------
__global__ __launch_bounds__(256) void layernorm_k(const float* __restrict__ x, float* __restrict__ out,
    const float* __restrict__ g, const float* __restrict__ b) {
  __shared__ float lds[256];
  long long t = blockIdx.x;
  float v = x[t * 256 + threadIdx.x];
  float s  = blk_reduce_sum(v, lds);
  float s2 = blk_reduce_sum(v * v, lds);
  float m = s * (1.f / 256.f);
  float var = s2 * (1.f / 256.f) - m * m;
  float rinv = 1.f / sqrtf(var + 1e-5f);
  out[t * 256 + threadIdx.x] = (v - m) * rinv * g[threadIdx.x] + b[threadIdx.x];
}

// ---------------- row softmax (unnormalized exp; stores 1/sum per row) ----------------
__global__ __launch_bounds__(256) void softmax_k(float* __restrict__ S, float* __restrict__ den, int n) {
  __shared__ float lds[256];
  float* p = S + (long long)blockIdx.x * n;
  float mx = -3.4e38f;
  for (int i = threadIdx.x; i < n; i += 256) mx = fmaxf(mx, p[i]);
  mx = blk_reduce_max(mx, lds);
  float s = 0.f;
  for (int i = threadIdx.x; i < n; i += 256) { float e = __expf(p[i] - mx); p[i] = e; s += e; }
  s = blk_reduce_sum(s, lds);
  if (threadIdx.x == 0) den[blockIdx.x] = 1.f / s;
}

// ---------------- PV split-K reduce: out[i] = den[i>>8] * sum_c part[c][i] ----------------
__global__ __launch_bounds__(256) void pv_reduce_k(const float* __restrict__ part,
    const float* __restrict__ den, float* __restrict__ out, int nchunk) {
  long long i = (long long)blockIdx.x * 256 + threadIdx.x;
  float s = 0.f;
  for (int c = 0; c < nchunk; ++c) s += part[(long long)c * 802816 + i];
  out[i] = s * den[i >> 8];
}

// ---------------- GEGLU ----------------
__global__ void geglu_k(float* __restrict__ p, int ntok) {
  int idx = blockIdx.x * 256 + threadIdx.x;
  if (idx >= ntok * 1024) return;
  int t = idx >> 10, j = idx & 1023;
  float a  = p[t * 2048 + j];
  float gt = p[t * 2048 + 1024 + j];
  float ge = 0.5f * gt * (1.f + erff(gt * 0.70710678118654752f));
  p[t * 2048 + j] = a * ge;
}

// ---------------- degenerate cross-attn ----------------
__global__ __launch_bounds__(256) void crossattn_vec_k(const float* __restrict__ cond,
    const float* __restrict__ v2w, const float* __restrict__ o2w, const float* __restrict__ o2b,
    float* __restrict__ o2buf) {
  __shared__ float kv[256];
  int b = blockIdx.x, oc = threadIdx.x;
  float s = 0.f;
  for (int j = 0; j < 512; ++j) s = fmaf(cond[b * 512 + j], v2w[oc * 512 + j], s);
  kv[oc] = s; __syncthreads();
  float o = o2b[oc];
  for (int ic = 0; ic < 256; ++ic) o = fmaf(kv[ic], o2w[oc * 256 + ic], o);
  o2buf[b * 256 + oc] = o;
}
__global__ void bcast_add_k(float* __restrict__ T, const float* __restrict__ o2buf, int ntok_per_b) {
  long long idx = (long long)blockIdx.x * 256 + threadIdx.x;
  int c = (int)(idx & 255);
  long long tb = idx >> 8;
  int b = (int)(tb / ntok_per_b);
  T[idx] += o2buf[b * 256 + c];
}

// ---------------- final 7x7 conv + tanh ----------------
__global__ __launch_bounds__(256) void conv_final_k(const float* __restrict__ in,
    const float* __restrict__ w, const float* __restrict__ bias, float* __restrict__ out) {
  __shared__ float wl[3 * 64 * 49];
  for (int i = threadIdx.x; i < 3 * 64 * 49; i += 256) wl[i] = w[i];
  __syncthreads();
  int b = blockIdx.y;
  int p = blockIdx.x * 256 + threadIdx.x;
  int y = p / 224, x = p % 224;
  int iy[7], ix[7];
  #pragma unroll
  for (int t = 0; t < 7; ++t) {
    int a = y + t - 3; iy[t] = (a < 0) ? -a : ((a >= 224) ? 446 - a : a);
    int c = x + t - 3; ix[t] = (c < 0) ? -c : ((c >= 224) ? 446 - c : c);
  }
  float a0 = bias[0], a1 = bias[1], a2 = bias[2];
  for (int ic = 0; ic < 64; ++ic) {
    const float* ip = in + (long long)(b * 64 + ic) * N224;
    const float* w0 = &wl[(0 * 64 + ic) * 49];
    const float* w1 = &wl[(1 * 64 + ic) * 49];
    const float* w2 = &wl[(2 * 64 + ic) * 49];
    #pragma unroll
    for (int ky = 0; ky < 7; ++ky) {
      const float* rp = ip + iy[ky] * 224;
      #pragma unroll
      for (int kx = 0; kx < 7; ++kx) {
        float v = rp[ix[kx]];
        int t = ky * 7 + kx;
        a0 = fmaf(v, w0[t], a0);
        a1 = fmaf(v, w1[t], a1);
        a2 = fmaf(v, w2[t], a2);
      }
    }
  }
  long long ob = (long long)b * 3 * N224 + p;
  out[ob]            = tanhf(a0);
  out[ob + N224]     = tanhf(a1);
  out[ob + 2 * N224] = tanhf(a2);
}

// ---------------- gaussian blur * eps ----------------
__global__ void blur_k(const float* __restrict__ x, float* __restrict__ out, const int* __restrict__ epsp) {
  int idx = blockIdx.x * 256 + threadIdx.x;
  int xp = idx % 224;
  int y  = (idx / 224) % 224;
  int bc = idx / N224;
  const float* p = x + (long long)bc * N224;
  const float kc = 0.20417996f, k1 = 0.12384140f, k2 = 0.07511360f;
  float s = 0.f;
  #pragma unroll
  for (int dy = -1; dy <= 1; ++dy) {
    int yy = y + dy;
    if (yy < 0 || yy >= 224) continue;
    #pragma unroll
    for (int dx = -1; dx <= 1; ++dx) {
      int xx = xp + dx;
      if (xx < 0 || xx >= 224) continue;
      float wgt = (dy == 0 && dx == 0) ? kc : ((dy != 0 && dx != 0) ? k2 : k1);
      s = fmaf(p[yy * 224 + xx], wgt, s);
    }
  }
  out[idx] = s * (float)epsp[0];
}

// ---------------- host ----------------
static inline MArgs MA() { MArgs g = {}; g.alpha = 1.f; return g; }

template<int AMODE, int BMN, int KSTEP, int BSPLIT>
static inline void mgl(hipStream_t s, const MArgs& g, int zb) {
  dim3 grid(DIVUP(g.N, BMN), DIVUP(g.M, BMN), zb);
  mg_k<AMODE, BMN, KSTEP, BSPLIT><<<grid, 256, 0, s>>>(g);
}

extern "C" void kernel_launch(void* const* d_in, const int* in_sizes, int n_in,
                              void* d_out, int out_size, void* d_ws, size_t ws_size,
                              hipStream_t stream) {
  (void)in_sizes; (void)n_in; (void)out_size; (void)ws_size;
  const float* input = (const float*)d_in[0];
  const float* cond  = (const float*)d_in[1];
  const float* sn_w  = (const float*)d_in[2];
  const float* sn_u  = (const float*)d_in[3];
  const float* c1_w  = (const float*)d_in[4];
  const float* bn1_g = (const float*)d_in[5];
  const float* bn1_b = (const float*)d_in[6];
  const float* c2_w  = (const float*)d_in[7];
  const float* bn2_g = (const float*)d_in[8];
  const float* bn2_b = (const float*)d_in[9];
  const float* c3_w  = (const float*)d_in[10];
  const float* bn3_g = (const float*)d_in[11];
  const float* bn3_b = (const float*)d_in[12];
  const float* res_w = (const float*)d_in[13];
  const float* res_g = (const float*)d_in[14];
  const float* res_b = (const float*)d_in[15];
  const float* gn_g  = (const float*)d_in[16];
  const float* gn_b  = (const float*)d_in[17];
  const float* pin_w = (const float*)d_in[18];
  const float* pin_b = (const float*)d_in[19];
  const float* q1w   = (const float*)d_in[20];
  const float* k1w   = (const float*)d_in[21];
  const float* v1w   = (const float*)d_in[22];
  const float* o1w   = (const float*)d_in[23];
  const float* o1b   = (const float*)d_in[24];
  /* 25 st_q2, 26 st_k2: dead (ctx length 1 -> softmax == 1) */
  const float* v2w   = (const float*)d_in[27];
  const float* o2w   = (const float*)d_in[28];
  const float* o2b   = (const float*)d_in[29];
  const float* ffpw  = (const float*)d_in[30];
  const float* ffpb  = (const float*)d_in[31];
  const float* ffow  = (const float*)d_in[32];
  const float* ffob  = (const float*)d_in[33];
  const float* ln1g  = (const float*)d_in[34];
  const float* ln1b  = (const float*)d_in[35];
  /* 36,37: ln2 dead */
  const float* ln3g  = (const float*)d_in[38];
  const float* ln3b  = (const float*)d_in[39];
  const float* poutw = (const float*)d_in[40];
  const float* poutb = (const float*)d_in[41];
  const float* up1w  = (const float*)d_in[42];
  const float* up1g  = (const float*)d_in[43];
  const float* up1b  = (const float*)d_in[44];
  const float* up2w  = (const float*)d_in[45];
  const float* up2g  = (const float*)d_in[46];
  const float* up2b  = (const float*)d_in[47];
  const float* cfw   = (const float*)d_in[48];
  const float* cfb   = (const float*)d_in[49];
  const int*   epsp  = (const int*)d_in[50];

  const long long S56 = (long long)C4 * N56;      // 802816

  // ---- workspace layout (~203 MB, with aliasing) ----
  float* A1   = (float*)d_ws;                      // 12,845,056 f  (4x64x224x224)
  float* A2   = A1 + 12845056;                     //  6,422,528 f  (4x128x112x112)
  float* SIMb = A2 + 6422528;                      //  9,834,496 f  (3136^2)
  float* X    = SIMb + 9834496;                    //  3,211,264 f
  float* T    = X + 3211264;
  float* Hb   = T + 3211264;                       // also AO (attention out)
  float* Qb   = Hb + 3211264;
  float* Kb   = Qb + 3211264;
  float* Vt   = Kb + 3211264;                      // V transposed (ch-major)
  ushort_t* TFWh = (ushort_t*)(Vt + 3211264);      // 2,359,296 us
  ushort_t* TFWl = TFWh + 2359296;
  float* Zb = (float*)(TFWl + 2359296);            // 64 f
  float* O2 = Zb + 64;                             // 1024 f
  float* Sden = O2 + 1024;                         // 3136 f (softmax denominators)
  // overlays:
  ushort_t* RESW = (ushort_t*)A1;                  // res conv weights, live c2..res5
  ushort_t* SC = (ushort_t*)SIMb;                  // small conv weights (SIMb overlay!)
  ushort_t* c1h = SC,            * c1l = c1h + 100352;   // live: before transformer(0)
  ushort_t* c2h = c1l + 100352,  * c2l = c2h + 110592;
  ushort_t* c3h = c2l + 110592,  * c3l = c3h + 368640;
  ushort_t* u1h = c3l + 368640,  * u1l = u1h + 294912;   // prepped AFTER transformers
  ushort_t* u2h = u1l + 294912,  * u2l = u2h + 73728;
  float* CF = SIMb + 948224;                       // 602,112 f, final phase only
  float* FF = A2;                                  // per-batch FF buffer (alias)
  float* PVP = A2;                                 // PV split-K partials: 7 x 802,816 f = 5.6M f (alias)

  // per-tf split-weight offsets (elements)
  const int TFQ = 0, TFK = 65536, TFV = 131072, TFO1 = 196608, TFPIN = 262144,
            TFPOUT = 327680, TFFFP = 393216, TFFFO = 917504, TFSZ = 1179648;

  // ---- 1) z + weight prep ----
  spectral_z_k<<<1, 256, 0, stream>>>(cond, sn_w, sn_u, Zb);
  prep_conv_k<<<DIVUP(64 * 49 * 32, 256), 256, 0, stream>>>(c1_w, c1h, c1l, 64, 19, 32, 7);
  prep_conv_k<<<DIVUP(128 * 9 * 96, 256), 256, 0, stream>>>(c2_w, c2h, c2l, 128, 80, 96, 3);
  prep_conv_k<<<DIVUP(256 * 9 * 160, 256), 256, 0, stream>>>(c3_w, c3h, c3l, 256, 144, 160, 3);
  for (int i = 0; i < 2; ++i) {
    ushort_t* bh = TFWh + i * TFSZ; ushort_t* bl = TFWl + i * TFSZ;
    prep_lin_k<<<256, 256, 0, stream>>>(q1w  + (size_t)i * 65536, bh + TFQ,   bl + TFQ,   65536);
    prep_lin_k<<<256, 256, 0, stream>>>(k1w  + (size_t)i * 65536, bh + TFK,   bl + TFK,   65536);
    prep_lin_k<<<256, 256, 0, stream>>>(v1w  + (size_t)i * 65536, bh + TFV,   bl + TFV,   65536);
    prep_lin_k<<<256, 256, 0, stream>>>(o1w  + (size_t)i * 65536, bh + TFO1,  bl + TFO1,  65536);
    prep_lin_k<<<256, 256, 0, stream>>>(pin_w + (size_t)i * 65536, bh + TFPIN, bl + TFPIN, 65536);
    prep_lin_k<<<256, 256, 0, stream>>>(poutw + (size_t)i * 65536, bh + TFPOUT, bl + TFPOUT, 65536);
    prep_lin_k<<<2048, 256, 0, stream>>>(ffpw + (size_t)i * 524288, bh + TFFFP, bl + TFFFP, 524288);
    prep_lin_k<<<1024, 256, 0, stream>>>(ffow + (size_t)i * 262144, bh + TFFFO, bl + TFFFO, 262144);
  }

  // ---- 2) c1: 7x7 reflect(3), (3+16z)->64, BN+ReLU ----
  {
    MArgs g = MA();
    g.Xp = input; g.Xbatch = 3LL * N224; g.z = Zb; g.Cin = 3;
    g.Bh = c1h; g.Bl = c1l; g.Bstride = 1568;
    g.C = A1; g.Cm = 1; g.Cn = N224; g.Cbatch = 64LL * N224;
    g.scale = bn1_g; g.bias = bn1_b; g.alpha = BN_ALPHA; g.relu = 1;
    g.M = N224; g.N = 64; g.ICP = 32; g.NPH = 49;
    g.KS = 7; g.Hin = 224; g.Win = 224; g.Wout = 224; g.stride = 1; g.pad = 3; g.reflect = 1;
    mgl<1, 64, 32, 1>(stream, g, BB);
  }
  // ---- 3) c2: 3x3 s2, (64+16z)->128 ----
  {
    MArgs g = MA();
    g.Xp = A1; g.Xbatch = 64LL * N224; g.z = Zb; g.Cin = 64;
    g.Bh = c2h; g.Bl = c2l; g.Bstride = 864;
    g.C = A2; g.Cm = 1; g.Cn = N112; g.Cbatch = 128LL * N112;
    g.scale = bn2_g; g.bias = bn2_b; g.alpha = BN_ALPHA; g.relu = 1;
    g.M = N112; g.N = 128; g.ICP = 96; g.NPH = 9;
    g.KS = 3; g.Hin = 224; g.Win = 224; g.Wout = 112; g.stride = 2; g.pad = 1; g.reflect = 0;
    mgl<1, 64, 32, 1>(stream, g, BB);
  }
  // ---- prep resblock weights into A1 overlay (A1 activations dead after c2) ----
  for (int j = 0; j < 12; ++j) {
    ushort_t* bh = RESW + (size_t)j * 1179648;
    prep_conv_k<<<DIVUP(256 * 9 * 256, 256), 256, 0, stream>>>(
        res_w + (size_t)j * 589824, bh, bh + 589824, 256, 256, 256, 3);
  }
  // ---- 4) c3: 3x3 s2, (128+16z)->256 ----
  {
    MArgs g = MA();
    g.Xp = A2; g.Xbatch = 128LL * N112; g.z = Zb; g.Cin = 128;
    g.Bh = c3h; g.Bl = c3l; g.Bstride = 1440;
    g.C = X; g.Cm = 1; g.Cn = N56; g.Cbatch = S56;
    g.scale = bn3_g; g.bias = bn3_b; g.alpha = BN_ALPHA; g.relu = 1;
    g.M = N56; g.N = 256; g.ICP = 160; g.NPH = 9;
    g.KS = 3; g.Hin = 112; g.Win = 112; g.Wout = 56; g.stride = 2; g.pad = 1; g.reflect = 0;
    mgl<1, 64, 32, 1>(stream, g, BB);
  }

  auto resconv = [&](int j, const float* src, float* dst, int relu, const float* resid) {
    MArgs g = MA();
    g.Xp = src; g.Xbatch = S56; g.Cin = 256;
    ushort_t* bh = RESW + (size_t)j * 1179648;
    g.Bh = bh; g.Bl = bh + 589824; g.Bstride = 2304;
    g.C = dst; g.Cm = 1; g.Cn = N56; g.Cbatch = S56;
    g.scale = res_g + j * 256; g.bias = res_b + j * 256; g.alpha = BN_ALPHA; g.relu = relu;
    if (resid) { g.resid = resid; g.Rm = 1; g.Rn = N56; g.Rbatch = S56; }
    g.M = N56; g.N = 256; g.ICP = 256; g.NPH = 9;
    g.KS = 3; g.Hin = 56; g.Win = 56; g.Wout = 56; g.stride = 1; g.pad = 1; g.reflect = 1;
    mgl<1, 64, 64, 1>(stream, g, BB);
  };
  auto resblock = [&](int r) {
    resconv(r * 2, X, Hb, 1, nullptr);
    resconv(r * 2 + 1, Hb, X, 0, X);
  };

  auto lin = [&](int i, int woff, const float* A, long long Am, long long Ak, long long Ab,
                 float* C, long long Cm, long long Cn, long long Cb,
                 const float* bias, const float* resid, long long Rm, long long Rn, long long Rb,
                 int M, int N, int K, float alpha, int zb) {
    MArgs g = MA();
    g.A = A; g.Am = Am; g.Ak = Ak; g.Abatch = Ab;
    g.Bh = TFWh + i * TFSZ + woff; g.Bl = TFWl + i * TFSZ + woff; g.Bstride = K;
    g.C = C; g.Cm = Cm; g.Cn = Cn; g.Cbatch = Cb;
    g.bias = bias;
    if (resid) { g.resid = resid; g.Rm = Rm; g.Rn = Rn; g.Rbatch = Rb; }
    g.alpha = alpha; g.M = M; g.N = N; g.ICP = K; g.NPH = 1;
    mgl<0, 64, 64, 1>(stream, g, zb);
  };

  auto transformer = [&](int i) {
    groupnorm_k<<<dim3(32, BB), 256, 0, stream>>>(X, Hb, gn_g + i * 256, gn_b + i * 256, 256, N56, 8);
    // proj_in: A = GN out (ch-major), C = tokens T
    lin(i, TFPIN, Hb, 1, N56, S56, T, 256, 1, S56, pin_b + i * 256,
        nullptr, 0, 0, 0, N56, 256, 256, 1.f, BB);
    layernorm_k<<<BB * N56, 256, 0, stream>>>(T, Hb, ln1g + i * 256, ln1b + i * 256);
    // Q,K token-major; V channel-major
    lin(i, TFQ, Hb, 256, 1, S56, Qb, 256, 1, S56, nullptr, nullptr, 0, 0, 0, N56, 256, 256, 1.f, BB);
    lin(i, TFK, Hb, 256, 1, S56, Kb, 256, 1, S56, nullptr, nullptr, 0, 0, 0, N56, 256, 256, 1.f, BB);
    lin(i, TFV, Hb, 256, 1, S56, Vt, 1, N56, S56, nullptr, nullptr, 0, 0, 0, N56, 256, 256, 1.f, BB);
    for (int b = 0; b < BB; ++b) {
      {  // QK^T -> SIM (128 tile, 625 blocks)
        MArgs g = MA();
        g.A = Qb + (size_t)b * S56; g.Am = 256; g.Ak = 1; g.Abatch = 0;
        g.Bf = Kb + (size_t)b * S56; g.Bstride = 256; g.Bbatch = 0;
        g.C = SIMb; g.Cm = N56; g.Cn = 1; g.Cbatch = 0;
        g.alpha = 0.0625f; g.M = N56; g.N = N56; g.ICP = 256; g.NPH = 1;
        mgl<0, 128, 32, 0>(stream, g, 1);
      }
      softmax_k<<<N56, 256, 0, stream>>>(SIMb, Sden, N56);
      {  // PV split-K: 7 chunks of 448, partials into PVP
        MArgs g = MA();
        g.A = SIMb; g.Am = N56; g.Ak = 1; g.Abatch = 448;
        g.Bf = Vt + (size_t)b * S56; g.Bstride = N56; g.Bbatch = 448;
        g.C = PVP; g.Cm = 256; g.Cn = 1; g.Cbatch = 802816;
        g.M = N56; g.N = 256; g.ICP = 448; g.NPH = 1;
        mgl<0, 64, 64, 0>(stream, g, 7);
      }
      pv_reduce_k<<<3136, 256, 0, stream>>>(PVP, Sden, Hb + (size_t)b * S56, 7);
    }
    // out proj + residual into T (A = Hb = attention out)
    lin(i, TFO1, Hb, 256, 1, S56, T, 256, 1, S56, o1b + i * 256,
        T, 256, 1, S56, N56, 256, 256, 1.f, BB);
    crossattn_vec_k<<<BB, 256, 0, stream>>>(cond, v2w + (size_t)i * 131072,
                                            o2w + (size_t)i * 65536, o2b + i * 256, O2);
    bcast_add_k<<<BB * N56, 256, 0, stream>>>(T, O2, N56);
    layernorm_k<<<BB * N56, 256, 0, stream>>>(T, Hb, ln3g + i * 256, ln3b + i * 256);
    for (int b = 0; b < BB; ++b) {
      lin(i, TFFFP, Hb + (size_t)b * S56, 256, 1, 0, FF, 2048, 1, 0, ffpb + i * 2048,
          nullptr, 0, 0, 0, N56, 2048, 256, 1.f, 1);
      geglu_k<<<DIVUP(N56 * 1024, 256), 256, 0, stream>>>(FF, N56);
      lin(i, TFFFO, FF, 2048, 1, 0, T + (size_t)b * S56, 256, 1, 0, ffob + i * 256,
          T + (size_t)b * S56, 256, 1, 0, N56, 256, 1024, 1.f, 1);
    }
    // proj_out: tokens -> NCHW + residual X
    lin(i, TFPOUT, T, 256, 1, S56, X, 1, N56, S56, poutb + i * 256,
        X, 1, N56, S56, N56, 256, 256, 1.f, BB);
  };

  resblock(0); resblock(1);
  transformer(0);
  resblock(2); resblock(3);
  transformer(1);
  resblock(4); resblock(5);

  // ---- prep convT weights NOW (SC overlay of SIMb was clobbered by attention SIM) ----
  prep_convt_k<<<DIVUP(128 * 9 * 256, 256), 256, 0, stream>>>(up1w, u1h, u1l, 256, 128);
  prep_convt_k<<<DIVUP(64 * 9 * 128, 256), 256, 0, stream>>>(up2w, u2h, u2l, 128, 64);

  // ---- up1: convT 256->128, 56->112 ----
  {
    MArgs g = MA();
    g.Xp = X; g.Xbatch = S56; g.Cin = 256;
    g.Bh = u1h; g.Bl = u1l; g.Bstride = 2304;
    g.C = A2; g.Cm = 1; g.Cn = N112; g.Cbatch = 128LL * N112;
    g.scale = up1g; g.bias = up1b; g.alpha = BN_ALPHA; g.relu = 1;
    g.M = N112; g.N = 128; g.ICP = 256; g.NPH = 9;
    g.KS = 3; g.Hin = 56; g.Win = 56; g.Wout = 112;
    mgl<2, 64, 64, 1>(stream, g, BB);
  }
  // ---- up2: convT 128->64, 112->224 ----
  {
    MArgs g = MA();
    g.Xp = A2; g.Xbatch = 128LL * N112; g.Cin = 128;
    g.Bh = u2h; g.Bl = u2l; g.Bstride = 1152;
    g.C = A1; g.Cm = 1; g.Cn = N224; g.Cbatch = 64LL * N224;
    g.scale = up2g; g.bias = up2b; g.alpha = BN_ALPHA; g.relu = 1;
    g.M = N224; g.N = 64; g.ICP = 128; g.NPH = 9;
    g.KS = 3; g.Hin = 112; g.Win = 112; g.Wout = 224;
    mgl<2, 64, 64, 1>(stream, g, BB);
  }

  conv_final_k<<<dim3(N224 / 256, BB), 256, 0, stream>>>(A1, cfw, cfb, CF);
  blur_k<<<DIVUP(BB * 3 * N224, 256), 256, 0, stream>>>(CF, (float*)d_out, epsp);
}

// Round 6
// 7455.748 us; speedup vs baseline: 2.5825x; 1.1723x over previous
//
#include <hip/hip_runtime.h>
#include <math.h>

#ifndef DIVUP
#define DIVUP(a,b) (((a)+(b)-1)/(b))
#endif

typedef unsigned short ushort_t;
typedef __attribute__((ext_vector_type(8))) short v8s;
typedef __attribute__((ext_vector_type(4))) float v4f;

#define BB 4
#define NZ 16
#define C4 256
#define N56 3136
#define N112 12544
#define N224 50176

static const float BN_ALPHA = 0.99999500003749967f;  // 1/sqrt(1+1e-5)

// ---------------- helpers ----------------
__device__ inline int refl_idx(int i, int n) {
  if (i < 0) i = -i;
  if (i >= n) i = 2 * n - 2 - i;
  return i;
}

// RNE split: v ~= hi + lo (both bf16)
__device__ inline void bsplit(float v, ushort_t& h, ushort_t& l) {
  unsigned b = __float_as_uint(v);
  unsigned r = (b + 0x7FFFu + ((b >> 16) & 1u)) & 0xFFFF0000u;
  h = (ushort_t)(r >> 16);
  float lo = v - __uint_as_float(r);
  unsigned bl_ = __float_as_uint(lo);
  unsigned rl = bl_ + 0x7FFFu + ((bl_ >> 16) & 1u);
  l = (ushort_t)(rl >> 16);
}

__device__ inline float blk_reduce_sum(float v, float* lds) {
  int t = threadIdx.x;
  lds[t] = v; __syncthreads();
  for (int s = 128; s > 0; s >>= 1) { if (t < s) lds[t] += lds[t + s]; __syncthreads(); }
  float r = lds[0]; __syncthreads();
  return r;
}
__device__ inline float blk_reduce_max(float v, float* lds) {
  int t = threadIdx.x;
  lds[t] = v; __syncthreads();
  for (int s = 128; s > 0; s >>= 1) { if (t < s) lds[t] = fmaxf(lds[t], lds[t + s]); __syncthreads(); }
  float r = lds[0]; __syncthreads();
  return r;
}

// ---------------- MFMA GEMM (64x64 tile, KSTEP=32, double-buffered LDS) ----------------
// C[b][m][n] = act( alpha*scale[n] * sum_k A[m][k]*W[n][k] + bias[n] + resid )
// AMODE: 0 strided A; 1 implicit im2col conv (phase-major K, +z); 2 implicit convT
// BSPLIT: 1 = B pre-split ushort hi/lo; 0 = B fp32 (split inline)
// relu: 0 none, 1 relu, 2 tanh
struct MArgs {
  const float* A; long long Am, Ak, Abatch;          // AMODE 0
  const float* Xp; long long Xbatch;                 // AMODE 1/2 (NCHW input)
  const float* z;                                    // appended channels (AMODE 1)
  const ushort_t* Bh; const ushort_t* Bl;            // BSPLIT=1
  const float* Bf; long long Bbatch;                 // BSPLIT=0
  long long Bstride;                                 // row length (= padded K)
  float* C; long long Cm, Cn, Cbatch;
  const float* scale; const float* bias;
  const float* resid; long long Rm, Rn, Rbatch;
  float alpha; int relu;
  int M, N;
  int ICP, NPH;                                      // K = ICP*NPH (ICP mult of 32)
  int Cin;                                           // real channels (conv)
  int KS, Hin, Win, Wout, stride, pad, reflect;
};

template<int AMODE, int BSPLIT>
__global__ __launch_bounds__(256, 3) void mg_k(MArgs g) {
  constexpr int BMN = 64, EPT = 8, LDSW = 40;  // pitch 80B, 16B-aligned
  __shared__ __align__(16) ushort_t sAh[2][BMN * LDSW];
  __shared__ __align__(16) ushort_t sAl[2][BMN * LDSW];
  __shared__ __align__(16) ushort_t sBh[2][BMN * LDSW];
  __shared__ __align__(16) ushort_t sBl[2][BMN * LDSW];

  const int tid = threadIdx.x;
  const int b = blockIdx.z;
  const int m0 = blockIdx.y * BMN, n0 = blockIdx.x * BMN;
  const int lane = tid & 63, w = tid >> 6;
  const int wm = (w >> 1) * 32, wn = (w & 1) * 32;

  const int srow = tid & 63;
  const int skoff = (tid >> 6) * EPT;

  // ---- A setup ----
  int am = m0 + srow; if (am >= g.M) am = g.M - 1;
  int cy = 0, cx = 0;
  const float* Aptr;
  if (AMODE == 0) {
    Aptr = g.A + (long long)b * g.Abatch + (long long)am * g.Am;
  } else {
    cy = am / g.Wout; cx = am - cy * g.Wout;
    Aptr = g.Xp + (long long)b * g.Xbatch;
  }
  const int HW = g.Hin * g.Win;

  // ---- B setup ----
  int bn = n0 + srow; if (bn >= g.N) bn = g.N - 1;
  const ushort_t* BhP = BSPLIT ? (g.Bh + (long long)bn * g.Bstride + skoff) : nullptr;
  const ushort_t* BlP = BSPLIT ? (g.Bl + (long long)bn * g.Bstride + skoff) : nullptr;
  const float* BfP = BSPLIT ? nullptr : (g.Bf + (long long)b * g.Bbatch + (long long)bn * g.Bstride + skoff);

  // phase state (conv modes)
  int ph = 0, ic0 = 0, pbase = 0;
  bool pvalid = true;
  int kglob = 0;

  float areg[EPT];
  v8s bregh, bregl;
  float bregf[EPT];

  auto fetchA = [&]() {
    if (AMODE == 0) {
      const float* Ap = Aptr + (long long)(kglob + skoff) * g.Ak;
      if (g.Ak == 1) {
        float4 a0 = *(const float4*)Ap;
        float4 a1 = *(const float4*)(Ap + 4);
        areg[0] = a0.x; areg[1] = a0.y; areg[2] = a0.z; areg[3] = a0.w;
        areg[4] = a1.x; areg[5] = a1.y; areg[6] = a1.z; areg[7] = a1.w;
      } else {
        #pragma unroll
        for (int e = 0; e < EPT; ++e) areg[e] = Ap[(long long)e * g.Ak];
      }
      kglob += 32;
    } else {
      if (ic0 == 0) {
        int ky = ph / g.KS, kx = ph - ky * g.KS;
        if (AMODE == 1) {
          int iy = cy * g.stride + ky - g.pad;
          int ix = cx * g.stride + kx - g.pad;
          if (g.reflect) {
            iy = refl_idx(iy, g.Hin); ix = refl_idx(ix, g.Win); pvalid = true;
          } else {
            pvalid = (iy >= 0 && iy < g.Hin && ix >= 0 && ix < g.Win);
            if (iy < 0) iy = 0; if (iy >= g.Hin) iy = g.Hin - 1;
            if (ix < 0) ix = 0; if (ix >= g.Win) ix = g.Win - 1;
          }
          pbase = iy * g.Win + ix;
        } else {
          int iy2 = cy + ky - 1, ix2 = cx + kx - 1;
          pvalid = (iy2 >= 0) && (ix2 >= 0) && !(iy2 & 1) && !(ix2 & 1);
          int iy = iy2 >> 1, ix = ix2 >> 1;
          if (pvalid && (iy >= g.Hin || ix >= g.Win)) pvalid = false;
          if (!pvalid) { iy = 0; ix = 0; }
          pbase = iy * g.Win + ix;
        }
      }
      #pragma unroll
      for (int e = 0; e < EPT; ++e) {
        int ic = ic0 + skoff + e;
        float v = 0.f;
        if (pvalid) {
          if (ic < g.Cin) v = Aptr[pbase + ic * HW];
          else if (g.z && ic < g.Cin + NZ) v = g.z[b * NZ + (ic - g.Cin)];
        }
        areg[e] = v;
      }
      ic0 += 32; if (ic0 == g.ICP) { ic0 = 0; ++ph; }
    }
  };

  auto fetchB = [&](int k0) {
    if (BSPLIT) {
      bregh = *(const v8s*)(BhP + k0);
      bregl = *(const v8s*)(BlP + k0);
    } else {
      float4 f0 = *(const float4*)(BfP + k0);
      float4 f1 = *(const float4*)(BfP + k0 + 4);
      bregf[0] = f0.x; bregf[1] = f0.y; bregf[2] = f0.z; bregf[3] = f0.w;
      bregf[4] = f1.x; bregf[5] = f1.y; bregf[6] = f1.z; bregf[7] = f1.w;
    }
  };

  // stash current regs into LDS buffer `bi`
  auto stash = [&](int bi) {
    ushort_t ah[EPT], al[EPT];
    #pragma unroll
    for (int e = 0; e < EPT; ++e) bsplit(areg[e], ah[e], al[e]);
    *(v8s*)&sAh[bi][srow * LDSW + skoff] = *(v8s*)ah;
    *(v8s*)&sAl[bi][srow * LDSW + skoff] = *(v8s*)al;
    if (BSPLIT) {
      *(v8s*)&sBh[bi][srow * LDSW + skoff] = bregh;
      *(v8s*)&sBl[bi][srow * LDSW + skoff] = bregl;
    } else {
      ushort_t bh[EPT], bl[EPT];
      #pragma unroll
      for (int e = 0; e < EPT; ++e) bsplit(bregf[e], bh[e], bl[e]);
      *(v8s*)&sBh[bi][srow * LDSW + skoff] = *(v8s*)bh;
      *(v8s*)&sBl[bi][srow * LDSW + skoff] = *(v8s*)bl;
    }
  };

  v4f acc[2][2];
  #pragma unroll
  for (int i = 0; i < 2; ++i)
    #pragma unroll
    for (int j = 0; j < 2; ++j) acc[i][j] = (v4f)(0.f);

  const int nt = (g.ICP * g.NPH) / 32;
  const int fr = lane & 15, fk = (lane >> 4) * 8;

  // prologue: fill buf0 with t=0, prefetch regs for t=1
  fetchA(); fetchB(0);
  stash(0);
  if (nt > 1) { fetchA(); fetchB(32); }
  __syncthreads();

  for (int t = 0; t < nt; ++t) {
    const int cur = t & 1;
    if (t + 1 < nt) stash(cur ^ 1);                  // regs of t+1 -> other buffer
    if (t + 2 < nt) { fetchA(); fetchB((t + 2) * 32); }  // issue loads for t+2
    {
      v8s fah[2], fal[2], fbh[2], fbl[2];
      #pragma unroll
      for (int i = 0; i < 2; ++i) {
        fah[i] = *(const v8s*)&sAh[cur][(wm + i * 16 + fr) * LDSW + fk];
        fal[i] = *(const v8s*)&sAl[cur][(wm + i * 16 + fr) * LDSW + fk];
        fbh[i] = *(const v8s*)&sBh[cur][(wn + i * 16 + fr) * LDSW + fk];
        fbl[i] = *(const v8s*)&sBl[cur][(wn + i * 16 + fr) * LDSW + fk];
      }
      #pragma unroll
      for (int i = 0; i < 2; ++i)
        #pragma unroll
        for (int j = 0; j < 2; ++j) {
          acc[i][j] = __builtin_amdgcn_mfma_f32_16x16x32_bf16(fah[i], fbh[j], acc[i][j], 0, 0, 0);
          acc[i][j] = __builtin_amdgcn_mfma_f32_16x16x32_bf16(fah[i], fbl[j], acc[i][j], 0, 0, 0);
          acc[i][j] = __builtin_amdgcn_mfma_f32_16x16x32_bf16(fal[i], fbh[j], acc[i][j], 0, 0, 0);
        }
    }
    __syncthreads();
  }

  // epilogue: C/D layout col=lane&15, row=(lane>>4)*4+reg
  const int fq = lane >> 4;
  #pragma unroll
  for (int j = 0; j < 2; ++j) {
    int n = n0 + wn + j * 16 + fr;
    if (n >= g.N) continue;
    float sc = (g.scale ? g.scale[n] : 1.f) * g.alpha;
    float bs = g.bias ? g.bias[n] : 0.f;
    #pragma unroll
    for (int i = 0; i < 2; ++i) {
      int mb = m0 + wm + i * 16 + fq * 4;
      #pragma unroll
      for (int r = 0; r < 4; ++r) {
        int m = mb + r;
        if (m < g.M) {
          float v = acc[i][j][r] * sc + bs;
          if (g.resid) v += g.resid[(long long)b * g.Rbatch + (long long)m * g.Rm + (long long)n * g.Rn];
          if (g.relu == 1) v = fmaxf(v, 0.f);
          else if (g.relu == 2) v = tanhf(v);
          g.C[(long long)b * g.Cbatch + (long long)m * g.Cm + (long long)n * g.Cn] = v;
        }
      }
    }
  }
}

// ---------------- weight prep (fp32 -> bf16 hi/lo) ----------------
__global__ void prep_lin_k(const float* __restrict__ src, ushort_t* __restrict__ dh,
                           ushort_t* __restrict__ dl, int tot) {
  int i = blockIdx.x * 256 + threadIdx.x;
  if (i >= tot) return;
  bsplit(src[i], dh[i], dl[i]);
}

// src[n][Cin][KS][KS] -> dst[n][p*ICP+ic], p = ky*KS+kx
__global__ void prep_conv_k(const float* __restrict__ src, ushort_t* __restrict__ dh,
                            ushort_t* __restrict__ dl, int N, int Cin, int ICP, int KS) {
  int idx = blockIdx.x * 256 + threadIdx.x;
  int K2 = KS * KS;
  int tot = N * K2 * ICP;
  if (idx >= tot) return;
  int ic = idx % ICP;
  int p = (idx / ICP) % K2;
  int n = idx / (ICP * K2);
  float v = (ic < Cin) ? src[(n * Cin + ic) * K2 + p] : 0.f;
  bsplit(v, dh[idx], dl[idx]);
}

// src[Cin][Cout][3][3] -> dst[o][p*Cin+ic] with spatial flip
__global__ void prep_convt_k(const float* __restrict__ src, ushort_t* __restrict__ dh,
                             ushort_t* __restrict__ dl, int Cin, int Cout) {
  int idx = blockIdx.x * 256 + threadIdx.x;
  int tot = Cout * 9 * Cin;
  if (idx >= tot) return;
  int ic = idx % Cin;
  int p = (idx / Cin) % 9;
  int o = idx / (9 * Cin);
  int ky = p / 3, kx = p % 3;
  float v = src[((ic * Cout + o) * 3 + (2 - ky)) * 3 + (2 - kx)];
  bsplit(v, dh[idx], dl[idx]);
}

// ---------------- spectral norm -> z ----------------
__global__ __launch_bounds__(256) void spectral_z_k(const float* __restrict__ cond,
    const float* __restrict__ W, const float* __restrict__ u0, float* __restrict__ z) {
  __shared__ float v0[512];
  __shared__ float lds[256];
  __shared__ float wv[16];
  __shared__ float invs[2];
  int tid = threadIdx.x;
  float part = 0.f;
  #pragma unroll
  for (int r = 0; r < 2; ++r) {
    int j = tid + r * 256;
    float s = 0.f;
    #pragma unroll
    for (int i = 0; i < 16; ++i) s = fmaf(W[i * 512 + j], u0[i], s);
    v0[j] = s;
    part = fmaf(s, s, part);
  }
  float nv2 = blk_reduce_sum(part, lds);
  if (tid == 0) invs[0] = 1.f / (sqrtf(nv2) + 1e-12f);
  __syncthreads();
  float inv_nv = invs[0];
  {
    int i = tid >> 4, l = tid & 15;
    float s = 0.f;
    for (int jj = 0; jj < 32; ++jj) {
      int j = l + jj * 16;
      s = fmaf(W[i * 512 + j], v0[j], s);
    }
    lds[tid] = s; __syncthreads();
    if (l == 0) {
      float t = 0.f;
      for (int q = 0; q < 16; ++q) t += lds[(i << 4) + q];
      wv[i] = t * inv_nv;
    }
    __syncthreads();
    if (tid == 0) {
      float s2 = 0.f;
      for (int i2 = 0; i2 < 16; ++i2) s2 = fmaf(wv[i2], wv[i2], s2);
      float nw = sqrtf(s2);
      float sigma = s2 / (nw + 1e-12f);
      invs[1] = 1.f / sigma;
    }
    __syncthreads();
  }
  if (tid < 64) {
    int b = tid >> 4, i = tid & 15;
    float s = 0.f;
    for (int j = 0; j < 512; ++j) s = fmaf(cond[b * 512 + j], W[i * 512 + j], s);
    z[b * 16 + i] = s * invs[1];
  }
}

// ---------------- group norm (32 groups) ----------------
__global__ __launch_bounds__(256) void groupnorm_k(const float* __restrict__ x, float* __restrict__ out,
    const float* __restrict__ gam, const float* __restrict__ bet, int C, int HW, int cpg) {
  __shared__ float lds[256];
  int b = blockIdx.y, grp = blockIdx.x;
  long long base = ((long long)b * C + (long long)grp * cpg) * HW;
  int n = cpg * HW;
  float s = 0.f, s2 = 0.f;
  for (int i = threadIdx.x; i < n; i += 256) { float v = x[base + i]; s += v; s2 = fmaf(v, v, s2); }
  s  = blk_reduce_sum(s, lds);
  s2 = blk_reduce_sum(s2, lds);
  float m = s / (float)n;
  float var = s2 / (float)n - m * m;
  float rinv = 1.f / sqrtf(var + 1e-6f);
  for (int i = threadIdx.x; i < n; i += 256) {
    int c = grp * cpg + i / HW;
    out[base + i] = (x[base + i] - m) * rinv * gam[c] + bet[c];
  }
}

// ---------------- layer norm (dim 256, one token/block) ----------------
__global__ __launch_bounds__(256) void layernorm_k(const float* __restrict__ x, float* __restrict__ out,
    const float* __restrict__ g, const float* __restrict__ b) {
  __shared__ float lds[256];
  long long t = blockIdx.x;
  float v = x[t * 256 + threadIdx.x];
  float s  = blk_reduce_sum(v, lds);
  float s2 = blk_reduce_sum(v * v, lds);
  float m = s * (1.f / 256.f);
  float var = s2 * (1.f / 256.f) - m * m;
  float rinv = 1.f / sqrtf(var + 1e-5f);
  out[t * 256 + threadIdx.x] = (v - m) * rinv * g[threadIdx.x] + b[threadIdx.x];
}

// ---------------- row softmax (unnormalized exp; stores 1/sum per row) ----------------
__global__ __launch_bounds__(256) void softmax_k(float* __restrict__ S, float* __restrict__ den, int n) {
  __shared__ float lds[256];
  float* p = S + (long long)blockIdx.x * n;
  float mx = -3.4e38f;
  for (int i = threadIdx.x; i < n; i += 256) mx = fmaxf(mx, p[i]);
  mx = blk_reduce_max(mx, lds);
  float s = 0.f;
  for (int i = threadIdx.x; i < n; i += 256) { float e = __expf(p[i] - mx); p[i] = e; s += e; }
  s = blk_reduce_sum(s, lds);
  if (threadIdx.x == 0) den[blockIdx.x] = 1.f / s;
}

// ---------------- PV split-K reduce: out[i] = den[i>>8] * sum_c part[c][i] ----------------
__global__ __launch_bounds__(256) void pv_reduce_k(const float* __restrict__ part,
    const float* __restrict__ den, float* __restrict__ out, int nchunk) {
  long long i = (long long)blockIdx.x * 256 + threadIdx.x;
  float s = 0.f;
  for (int c = 0; c < nchunk; ++c) s += part[(long long)c * 802816 + i];
  out[i] = s * den[i >> 8];
}

// ---------------- GEGLU ----------------
__global__ void geglu_k(float* __restrict__ p, int ntok) {
  int idx = blockIdx.x * 256 + threadIdx.x;
  if (idx >= ntok * 1024) return;
  int t = idx >> 10, j = idx & 1023;
  float a  = p[t * 2048 + j];
  float gt = p[t * 2048 + 1024 + j];
  float ge = 0.5f * gt * (1.f + erff(gt * 0.70710678118654752f));
  p[t * 2048 + j] = a * ge;
}

// ---------------- degenerate cross-attn ----------------
__global__ __launch_bounds__(256) void crossattn_vec_k(const float* __restrict__ cond,
    const float* __restrict__ v2w, const float* __restrict__ o2w, const float* __restrict__ o2b,
    float* __restrict__ o2buf) {
  __shared__ float kv[256];
  int b = blockIdx.x, oc = threadIdx.x;
  float s = 0.f;
  for (int j = 0; j < 512; ++j) s = fmaf(cond[b * 512 + j], v2w[oc * 512 + j], s);
  kv[oc] = s; __syncthreads();
  float o = o2b[oc];
  for (int ic = 0; ic < 256; ++ic) o = fmaf(kv[ic], o2w[oc * 256 + ic], o);
  o2buf[b * 256 + oc] = o;
}
__global__ void bcast_add_k(float* __restrict__ T, const float* __restrict__ o2buf, int ntok_per_b) {
  long long idx = (long long)blockIdx.x * 256 + threadIdx.x;
  int c = (int)(idx & 255);
  long long tb = idx >> 8;
  int b = (int)(tb / ntok_per_b);
  T[idx] += o2buf[b * 256 + c];
}

// ---------------- gaussian blur * eps ----------------
__global__ void blur_k(const float* __restrict__ x, float* __restrict__ out, const int* __restrict__ epsp) {
  int idx = blockIdx.x * 256 + threadIdx.x;
  int xp = idx % 224;
  int y  = (idx / 224) % 224;
  int bc = idx / N224;
  const float* p = x + (long long)bc * N224;
  const float kc = 0.20417996f, k1 = 0.12384140f, k2 = 0.07511360f;
  float s = 0.f;
  #pragma unroll
  for (int dy = -1; dy <= 1; ++dy) {
    int yy = y + dy;
    if (yy < 0 || yy >= 224) continue;
    #pragma unroll
    for (int dx = -1; dx <= 1; ++dx) {
      int xx = xp + dx;
      if (xx < 0 || xx >= 224) continue;
      float wgt = (dy == 0 && dx == 0) ? kc : ((dy != 0 && dx != 0) ? k2 : k1);
      s = fmaf(p[yy * 224 + xx], wgt, s);
    }
  }
  out[idx] = s * (float)epsp[0];
}

// ---------------- host ----------------
static inline MArgs MA() { MArgs g = {}; g.alpha = 1.f; return g; }

template<int AMODE, int BSPLIT>
static inline void mgl(hipStream_t s, const MArgs& g, int zb) {
  dim3 grid(DIVUP(g.N, 64), DIVUP(g.M, 64), zb);
  mg_k<AMODE, BSPLIT><<<grid, 256, 0, s>>>(g);
}

extern "C" void kernel_launch(void* const* d_in, const int* in_sizes, int n_in,
                              void* d_out, int out_size, void* d_ws, size_t ws_size,
                              hipStream_t stream) {
  (void)in_sizes; (void)n_in; (void)out_size; (void)ws_size;
  const float* input = (const float*)d_in[0];
  const float* cond  = (const float*)d_in[1];
  const float* sn_w  = (const float*)d_in[2];
  const float* sn_u  = (const float*)d_in[3];
  const float* c1_w  = (const float*)d_in[4];
  const float* bn1_g = (const float*)d_in[5];
  const float* bn1_b = (const float*)d_in[6];
  const float* c2_w  = (const float*)d_in[7];
  const float* bn2_g = (const float*)d_in[8];
  const float* bn2_b = (const float*)d_in[9];
  const float* c3_w  = (const float*)d_in[10];
  const float* bn3_g = (const float*)d_in[11];
  const float* bn3_b = (const float*)d_in[12];
  const float* res_w = (const float*)d_in[13];
  const float* res_g = (const float*)d_in[14];
  const float* res_b = (const float*)d_in[15];
  const float* gn_g  = (const float*)d_in[16];
  const float* gn_b  = (const float*)d_in[17];
  const float* pin_w = (const float*)d_in[18];
  const float* pin_b = (const float*)d_in[19];
  const float* q1w   = (const float*)d_in[20];
  const float* k1w   = (const float*)d_in[21];
  const float* v1w   = (const float*)d_in[22];
  const float* o1w   = (const float*)d_in[23];
  const float* o1b   = (const float*)d_in[24];
  /* 25 st_q2, 26 st_k2: dead (ctx length 1 -> softmax == 1) */
  const float* v2w   = (const float*)d_in[27];
  const float* o2w   = (const float*)d_in[28];
  const float* o2b   = (const float*)d_in[29];
  const float* ffpw  = (const float*)d_in[30];
  const float* ffpb  = (const float*)d_in[31];
  const float* ffow  = (const float*)d_in[32];
  const float* ffob  = (const float*)d_in[33];
  const float* ln1g  = (const float*)d_in[34];
  const float* ln1b  = (const float*)d_in[35];
  /* 36,37: ln2 dead */
  const float* ln3g  = (const float*)d_in[38];
  const float* ln3b  = (const float*)d_in[39];
  const float* poutw = (const float*)d_in[40];
  const float* poutb = (const float*)d_in[41];
  const float* up1w  = (const float*)d_in[42];
  const float* up1g  = (const float*)d_in[43];
  const float* up1b  = (const float*)d_in[44];
  const float* up2w  = (const float*)d_in[45];
  const float* up2g  = (const float*)d_in[46];
  const float* up2b  = (const float*)d_in[47];
  const float* cfw   = (const float*)d_in[48];
  const float* cfb   = (const float*)d_in[49];
  const int*   epsp  = (const int*)d_in[50];

  const long long S56 = (long long)C4 * N56;      // 802816

  // ---- workspace layout (~203 MB, with aliasing) ----
  float* A1   = (float*)d_ws;                      // 12,845,056 f  (4x64x224x224)
  float* A2   = A1 + 12845056;                     //  6,422,528 f  (4x128x112x112)
  float* SIMb = A2 + 6422528;                      //  9,834,496 f  (3136^2)
  float* X    = SIMb + 9834496;                    //  3,211,264 f
  float* T    = X + 3211264;
  float* Hb   = T + 3211264;                       // also AO (attention out)
  float* Qb   = Hb + 3211264;
  float* Kb   = Qb + 3211264;
  float* Vt   = Kb + 3211264;                      // V transposed (ch-major)
  ushort_t* TFWh = (ushort_t*)(Vt + 3211264);      // 2,359,296 us
  ushort_t* TFWl = TFWh + 2359296;
  float* Zb = (float*)(TFWl + 2359296);            // 64 f
  float* O2 = Zb + 64;                             // 1024 f
  float* Sden = O2 + 1024;                         // 3136 f (softmax denominators)
  // overlays:
  ushort_t* RESW = (ushort_t*)A1;                  // res conv weights, live c2..res5
  ushort_t* SC = (ushort_t*)SIMb;                  // small conv weights (SIMb overlay!)
  ushort_t* c1h = SC,            * c1l = c1h + 100352;   // live: before transformer(0)
  ushort_t* c2h = c1l + 100352,  * c2l = c2h + 110592;
  ushort_t* c3h = c2l + 110592,  * c3l = c3h + 368640;
  ushort_t* u1h = c3l + 368640,  * u1l = u1h + 294912;   // prepped AFTER transformers
  ushort_t* u2h = u1l + 294912,  * u2l = u2h + 73728;
  ushort_t* cfh = u2l + 73728,   * cfl = cfh + 9408;     // final conv weights (3x49x64)
  float* CF = SIMb + 960000;                       // 602,112 f, final phase only
  float* FF = A2;                                  // per-batch FF buffer (alias)
  float* PVP = A2;                                 // PV split-K partials: 7 x 802,816 f (alias)

  // per-tf split-weight offsets (elements)
  const int TFQ = 0, TFK = 65536, TFV = 131072, TFO1 = 196608, TFPIN = 262144,
            TFPOUT = 327680, TFFFP = 393216, TFFFO = 917504, TFSZ = 1179648;

  // ---- 1) z + weight prep ----
  spectral_z_k<<<1, 256, 0, stream>>>(cond, sn_w, sn_u, Zb);
  prep_conv_k<<<DIVUP(64 * 49 * 32, 256), 256, 0, stream>>>(c1_w, c1h, c1l, 64, 19, 32, 7);
  prep_conv_k<<<DIVUP(128 * 9 * 96, 256), 256, 0, stream>>>(c2_w, c2h, c2l, 128, 80, 96, 3);
  prep_conv_k<<<DIVUP(256 * 9 * 160, 256), 256, 0, stream>>>(c3_w, c3h, c3l, 256, 144, 160, 3);
  for (int i = 0; i < 2; ++i) {
    ushort_t* bh = TFWh + i * TFSZ; ushort_t* bl = TFWl + i * TFSZ;
    prep_lin_k<<<256, 256, 0, stream>>>(q1w  + (size_t)i * 65536, bh + TFQ,   bl + TFQ,   65536);
    prep_lin_k<<<256, 256, 0, stream>>>(k1w  + (size_t)i * 65536, bh + TFK,   bl + TFK,   65536);
    prep_lin_k<<<256, 256, 0, stream>>>(v1w  + (size_t)i * 65536, bh + TFV,   bl + TFV,   65536);
    prep_lin_k<<<256, 256, 0, stream>>>(o1w  + (size_t)i * 65536, bh + TFO1,  bl + TFO1,  65536);
    prep_lin_k<<<256, 256, 0, stream>>>(pin_w + (size_t)i * 65536, bh + TFPIN, bl + TFPIN, 65536);
    prep_lin_k<<<256, 256, 0, stream>>>(poutw + (size_t)i * 65536, bh + TFPOUT, bl + TFPOUT, 65536);
    prep_lin_k<<<2048, 256, 0, stream>>>(ffpw + (size_t)i * 524288, bh + TFFFP, bl + TFFFP, 524288);
    prep_lin_k<<<1024, 256, 0, stream>>>(ffow + (size_t)i * 262144, bh + TFFFO, bl + TFFFO, 262144);
  }

  // ---- 2) c1: 7x7 reflect(3), (3+16z)->64, BN+ReLU ----
  {
    MArgs g = MA();
    g.Xp = input; g.Xbatch = 3LL * N224; g.z = Zb; g.Cin = 3;
    g.Bh = c1h; g.Bl = c1l; g.Bstride = 1568;
    g.C = A1; g.Cm = 1; g.Cn = N224; g.Cbatch = 64LL * N224;
    g.scale = bn1_g; g.bias = bn1_b; g.alpha = BN_ALPHA; g.relu = 1;
    g.M = N224; g.N = 64; g.ICP = 32; g.NPH = 49;
    g.KS = 7; g.Hin = 224; g.Win = 224; g.Wout = 224; g.stride = 1; g.pad = 3; g.reflect = 1;
    mgl<1, 1>(stream, g, BB);
  }
  // ---- 3) c2: 3x3 s2, (64+16z)->128 ----
  {
    MArgs g = MA();
    g.Xp = A1; g.Xbatch = 64LL * N224; g.z = Zb; g.Cin = 64;
    g.Bh = c2h; g.Bl = c2l; g.Bstride = 864;
    g.C = A2; g.Cm = 1; g.Cn = N112; g.Cbatch = 128LL * N112;
    g.scale = bn2_g; g.bias = bn2_b; g.alpha = BN_ALPHA; g.relu = 1;
    g.M = N112; g.N = 128; g.ICP = 96; g.NPH = 9;
    g.KS = 3; g.Hin = 224; g.Win = 224; g.Wout = 112; g.stride = 2; g.pad = 1; g.reflect = 0;
    mgl<1, 1>(stream, g, BB);
  }
  // ---- prep resblock weights into A1 overlay (A1 activations dead after c2) ----
  for (int j = 0; j < 12; ++j) {
    ushort_t* bh = RESW + (size_t)j * 1179648;
    prep_conv_k<<<DIVUP(256 * 9 * 256, 256), 256, 0, stream>>>(
        res_w + (size_t)j * 589824, bh, bh + 589824, 256, 256, 256, 3);
  }
  // ---- 4) c3: 3x3 s2, (128+16z)->256 ----
  {
    MArgs g = MA();
    g.Xp = A2; g.Xbatch = 128LL * N112; g.z = Zb; g.Cin = 128;
    g.Bh = c3h; g.Bl = c3l; g.Bstride = 1440;
    g.C = X; g.Cm = 1; g.Cn = N56; g.Cbatch = S56;
    g.scale = bn3_g; g.bias = bn3_b; g.alpha = BN_ALPHA; g.relu = 1;
    g.M = N56; g.N = 256; g.ICP = 160; g.NPH = 9;
    g.KS = 3; g.Hin = 112; g.Win = 112; g.Wout = 56; g.stride = 2; g.pad = 1; g.reflect = 0;
    mgl<1, 1>(stream, g, BB);
  }

  auto resconv = [&](int j, const float* src, float* dst, int relu, const float* resid) {
    MArgs g = MA();
    g.Xp = src; g.Xbatch = S56; g.Cin = 256;
    ushort_t* bh = RESW + (size_t)j * 1179648;
    g.Bh = bh; g.Bl = bh + 589824; g.Bstride = 2304;
    g.C = dst; g.Cm = 1; g.Cn = N56; g.Cbatch = S56;
    g.scale = res_g + j * 256; g.bias = res_b + j * 256; g.alpha = BN_ALPHA; g.relu = relu;
    if (resid) { g.resid = resid; g.Rm = 1; g.Rn = N56; g.Rbatch = S56; }
    g.M = N56; g.N = 256; g.ICP = 256; g.NPH = 9;
    g.KS = 3; g.Hin = 56; g.Win = 56; g.Wout = 56; g.stride = 1; g.pad = 1; g.reflect = 1;
    mgl<1, 1>(stream, g, BB);
  };
  auto resblock = [&](int r) {
    resconv(r * 2, X, Hb, 1, nullptr);
    resconv(r * 2 + 1, Hb, X, 0, X);
  };

  auto lin = [&](int i, int woff, const float* A, long long Am, long long Ak, long long Ab,
                 float* C, long long Cm, long long Cn, long long Cb,
                 const float* bias, const float* resid, long long Rm, long long Rn, long long Rb,
                 int M, int N, int K, float alpha, int zb) {
    MArgs g = MA();
    g.A = A; g.Am = Am; g.Ak = Ak; g.Abatch = Ab;
    g.Bh = TFWh + i * TFSZ + woff; g.Bl = TFWl + i * TFSZ + woff; g.Bstride = K;
    g.C = C; g.Cm = Cm; g.Cn = Cn; g.Cbatch = Cb;
    g.bias = bias;
    if (resid) { g.resid = resid; g.Rm = Rm; g.Rn = Rn; g.Rbatch = Rb; }
    g.alpha = alpha; g.M = M; g.N = N; g.ICP = K; g.NPH = 1;
    mgl<0, 1>(stream, g, zb);
  };

  auto transformer = [&](int i) {
    groupnorm_k<<<dim3(32, BB), 256, 0, stream>>>(X, Hb, gn_g + i * 256, gn_b + i * 256, 256, N56, 8);
    // proj_in: A = GN out (ch-major), C = tokens T
    lin(i, TFPIN, Hb, 1, N56, S56, T, 256, 1, S56, pin_b + i * 256,
        nullptr, 0, 0, 0, N56, 256, 256, 1.f, BB);
    layernorm_k<<<BB * N56, 256, 0, stream>>>(T, Hb, ln1g + i * 256, ln1b + i * 256);
    // Q,K token-major; V channel-major
    lin(i, TFQ, Hb, 256, 1, S56, Qb, 256, 1, S56, nullptr, nullptr, 0, 0, 0, N56, 256, 256, 1.f, BB);
    lin(i, TFK, Hb, 256, 1, S56, Kb, 256, 1, S56, nullptr, nullptr, 0, 0, 0, N56, 256, 256, 1.f, BB);
    lin(i, TFV, Hb, 256, 1, S56, Vt, 1, N56, S56, nullptr, nullptr, 0, 0, 0, N56, 256, 256, 1.f, BB);
    for (int b = 0; b < BB; ++b) {
      {  // QK^T -> SIM (64 tile, 2401 blocks)
        MArgs g = MA();
        g.A = Qb + (size_t)b * S56; g.Am = 256; g.Ak = 1; g.Abatch = 0;
        g.Bf = Kb + (size_t)b * S56; g.Bstride = 256; g.Bbatch = 0;
        g.C = SIMb; g.Cm = N56; g.Cn = 1; g.Cbatch = 0;
        g.alpha = 0.0625f; g.M = N56; g.N = N56; g.ICP = 256; g.NPH = 1;
        mgl<0, 0>(stream, g, 1);
      }
      softmax_k<<<N56, 256, 0, stream>>>(SIMb, Sden, N56);
      {  // PV split-K: 7 chunks of 448, partials into PVP
        MArgs g = MA();
        g.A = SIMb; g.Am = N56; g.Ak = 1; g.Abatch = 448;
        g.Bf = Vt + (size_t)b * S56; g.Bstride = N56; g.Bbatch = 448;
        g.C = PVP; g.Cm = 256; g.Cn = 1; g.Cbatch = 802816;
        g.M = N56; g.N = 256; g.ICP = 448; g.NPH = 1;
        mgl<0, 0>(stream, g, 7);
      }
      pv_reduce_k<<<3136, 256, 0, stream>>>(PVP, Sden, Hb + (size_t)b * S56, 7);
    }
    // out proj + residual into T (A = Hb = attention out)
    lin(i, TFO1, Hb, 256, 1, S56, T, 256, 1, S56, o1b + i * 256,
        T, 256, 1, S56, N56, 256, 256, 1.f, BB);
    crossattn_vec_k<<<BB, 256, 0, stream>>>(cond, v2w + (size_t)i * 131072,
                                            o2w + (size_t)i * 65536, o2b + i * 256, O2);
    bcast_add_k<<<BB * N56, 256, 0, stream>>>(T, O2, N56);
    layernorm_k<<<BB * N56, 256, 0, stream>>>(T, Hb, ln3g + i * 256, ln3b + i * 256);
    for (int b = 0; b < BB; ++b) {
      lin(i, TFFFP, Hb + (size_t)b * S56, 256, 1, 0, FF, 2048, 1, 0, ffpb + i * 2048,
          nullptr, 0, 0, 0, N56, 2048, 256, 1.f, 1);
      geglu_k<<<DIVUP(N56 * 1024, 256), 256, 0, stream>>>(FF, N56);
      lin(i, TFFFO, FF, 2048, 1, 0, T + (size_t)b * S56, 256, 1, 0, ffob + i * 256,
          T + (size_t)b * S56, 256, 1, 0, N56, 256, 1024, 1.f, 1);
    }
    // proj_out: tokens -> NCHW + residual X
    lin(i, TFPOUT, T, 256, 1, S56, X, 1, N56, S56, poutb + i * 256,
        X, 1, N56, S56, N56, 256, 256, 1.f, BB);
  };

  resblock(0); resblock(1);
  transformer(0);
  resblock(2); resblock(3);
  transformer(1);
  resblock(4); resblock(5);

  // ---- prep convT + final conv weights NOW (SC overlay of SIMb was clobbered by SIM) ----
  prep_convt_k<<<DIVUP(128 * 9 * 256, 256), 256, 0, stream>>>(up1w, u1h, u1l, 256, 128);
  prep_convt_k<<<DIVUP(64 * 9 * 128, 256), 256, 0, stream>>>(up2w, u2h, u2l, 128, 64);
  prep_conv_k<<<DIVUP(3 * 49 * 64, 256), 256, 0, stream>>>(cfw, cfh, cfl, 3, 64, 64, 7);

  // ---- up1: convT 256->128, 56->112 ----
  {
    MArgs g = MA();
    g.Xp = X; g.Xbatch = S56; g.Cin = 256;
    g.Bh = u1h; g.Bl = u1l; g.Bstride = 2304;
    g.C = A2; g.Cm = 1; g.Cn = N112; g.Cbatch = 128LL * N112;
    g.scale = up1g; g.bias = up1b; g.alpha = BN_ALPHA; g.relu = 1;
    g.M = N112; g.N = 128; g.ICP = 256; g.NPH = 9;
    g.KS = 3; g.Hin = 56; g.Win = 56; g.Wout = 112;
    mgl<2, 1>(stream, g, BB);
  }
  // ---- up2: convT 128->64, 112->224 ----
  {
    MArgs g = MA();
    g.Xp = A2; g.Xbatch = 128LL * N112; g.Cin = 128;
    g.Bh = u2h; g.Bl = u2l; g.Bstride = 1152;
    g.C = A1; g.Cm = 1; g.Cn = N224; g.Cbatch = 64LL * N224;
    g.scale = up2g; g.bias = up2b; g.alpha = BN_ALPHA; g.relu = 1;
    g.M = N224; g.N = 64; g.ICP = 128; g.NPH = 9;
    g.KS = 3; g.Hin = 112; g.Win = 112; g.Wout = 224;
    mgl<2, 1>(stream, g, BB);
  }
  // ---- final 7x7 conv (64->3, reflect 3) + tanh via MFMA GEMM ----
  {
    MArgs g = MA();
    g.Xp = A1; g.Xbatch = 64LL * N224; g.Cin = 64;
    g.Bh = cfh; g.Bl = cfl; g.Bstride = 3136;
    g.C = CF; g.Cm = 1; g.Cn = N224; g.Cbatch = 3LL * N224;
    g.bias = cfb; g.relu = 2;
    g.M = N224; g.N = 3; g.ICP = 64; g.NPH = 49;
    g.KS = 7; g.Hin = 224; g.Win = 224; g.Wout = 224; g.stride = 1; g.pad = 3; g.reflect = 1;
    mgl<1, 1>(stream, g, BB);
  }
  blur_k<<<DIVUP(BB * 3 * N224, 256), 256, 0, stream>>>(CF, (float*)d_out, epsp);
}